// Round 8
// baseline (9453.210 us; speedup 1.0000x reference)
//
#include <hip/hip_runtime.h>
#include <hip/hip_cooperative_groups.h>
#include <math.h>

namespace cg = cooperative_groups;

#define DEV __device__ __forceinline__

static constexpr int B_ = 128, T_ = 32, H_ = 512;
static constexpr int S_ = 2048, M_ = 64, OUT_ = 256;
static constexpr int VCS_ = 768;  // vc row stride: 256 (vt) + 453 (ctrl) padded to 768
static constexpr float EPSF = 1e-8f;

DEV float sigmoidf_(float x){ return 1.0f/(1.0f+expf(-x)); }
DEV float softplusf_(float x){ return fmaxf(x,0.0f) + log1pf(expf(-fabsf(x))); }

// ---- packed candidate: (monotonic(value) << 32) | ~idx  => u64 '>' == (value desc, idx asc)
DEV unsigned long long packCand(float v, unsigned idx){
  unsigned u = __float_as_uint(v);
  unsigned m = (u & 0x80000000u) ? ~u : (u | 0x80000000u);
  return ((unsigned long long)m << 32) | (unsigned)(~idx);
}
DEV float unpackVal(unsigned long long e){
  unsigned m = (unsigned)(e >> 32);
  unsigned u = (m & 0x80000000u) ? (m & 0x7FFFFFFFu) : ~m;
  return __uint_as_float(u);
}
DEV unsigned unpackIdx(unsigned long long e){ return ~(unsigned)e; }

DEV void cswp(unsigned long long &a, unsigned long long &b){
  if(a < b){ unsigned long long t=a; a=b; b=t; }   // larger first (descending)
}
// Batcher odd-even mergesort for 8, descending
DEV void sort8(unsigned long long* L){
  cswp(L[0],L[1]); cswp(L[2],L[3]); cswp(L[4],L[5]); cswp(L[6],L[7]);
  cswp(L[0],L[2]); cswp(L[1],L[3]); cswp(L[4],L[6]); cswp(L[5],L[7]);
  cswp(L[1],L[2]); cswp(L[5],L[6]);
  cswp(L[0],L[4]); cswp(L[1],L[5]); cswp(L[2],L[6]); cswp(L[3],L[7]);
  cswp(L[2],L[4]); cswp(L[3],L[5]);
  cswp(L[1],L[2]); cswp(L[3],L[4]); cswp(L[5],L[6]);
}
// bitonic merge of 16, descending (input must be bitonic)
DEV void bmerge16(unsigned long long* C){
  #pragma unroll
  for(int i=0;i<8;i++) cswp(C[i],C[i+8]);
  #pragma unroll
  for(int g=0;g<2;g++){ int o=g*8;
    cswp(C[o+0],C[o+4]); cswp(C[o+1],C[o+5]); cswp(C[o+2],C[o+6]); cswp(C[o+3],C[o+7]); }
  #pragma unroll
  for(int g=0;g<4;g++){ int o=g*4; cswp(C[o+0],C[o+2]); cswp(C[o+1],C[o+3]); }
  #pragma unroll
  for(int g=0;g<8;g++){ int o=g*2; cswp(C[o],C[o+1]); }
}
// X[0..7] desc, X[8..15] desc -> X[0..15] fully sorted desc
DEV void merge8x8(unsigned long long* X){
  unsigned long long C[16];
  #pragma unroll
  for(int i=0;i<8;i++){ C[i]=X[i]; C[8+i]=X[15-i]; }
  bmerge16(C);
  #pragma unroll
  for(int i=0;i<16;i++) X[i]=C[i];
}
// butterfly keep-8: each lane holds sorted-8 desc
DEV void butterfly8(unsigned long long* L, int maxMask){
  for(int mask=1; mask<=maxMask; mask<<=1){
    unsigned long long O[8], C[8];
    #pragma unroll
    for(int i=0;i<8;i++) O[i] = __shfl_xor(L[i], mask, 64);
    #pragma unroll
    for(int i=0;i<8;i++){ unsigned long long a=L[i], b=O[7-i]; C[i] = (a>b)?a:b; }
    cswp(C[0],C[4]); cswp(C[1],C[5]); cswp(C[2],C[6]); cswp(C[3],C[7]);
    cswp(C[0],C[2]); cswp(C[1],C[3]); cswp(C[4],C[6]); cswp(C[5],C[7]);
    cswp(C[0],C[1]); cswp(C[2],C[3]); cswp(C[4],C[5]); cswp(C[6],C[7]);
    #pragma unroll
    for(int i=0;i<8;i++) L[i]=C[i];
  }
}
// butterfly keep-16 over all 64 lanes (per-lane lists sorted-16 desc)
DEV void butterfly16(unsigned long long* L){
  for(int mask=1; mask<64; mask<<=1){
    unsigned long long O[16], C[16];
    #pragma unroll
    for(int i=0;i<16;i++) O[i] = __shfl_xor(L[i], mask, 64);
    #pragma unroll
    for(int i=0;i<16;i++){ unsigned long long a=L[i], b=O[15-i]; C[i] = (a>b)?a:b; }
    bmerge16(C);
    #pragma unroll
    for(int i=0;i<16;i++) L[i]=C[i];
  }
}

// ---------------- generic fp32 GEMM  C[M,N] = A[M,K] * Bm[N,K]^T ----------------
__global__ __launch_bounds__(256)
void k_gemm64(const float* __restrict__ A, int lda,
              const float* __restrict__ Bm, int ldb,
              float* __restrict__ C, int ldc,
              int kCount,
              const float* __restrict__ bias0, const float* __restrict__ bias1)
{
  const int BM=64, BN=64, BK=16, LDT=68;
  __shared__ float As[BK*LDT];
  __shared__ float Bs[BK*LDT];
  const int m0 = blockIdx.x*BM, n0 = blockIdx.y*BN;
  const int tid = threadIdx.x;
  const int tx = tid & 15, ty = tid >> 4;
  const int kStart = blockIdx.z * kCount;
  float acc[4][4] = {};
  const int row = tid >> 2, kk = (tid & 3) * 4;
  for(int k0 = kStart; k0 < kStart + kCount; k0 += BK){
    float4 av = *(const float4*)(A  + (size_t)(m0+row)*lda + k0 + kk);
    float4 bv = *(const float4*)(Bm + (size_t)(n0+row)*ldb + k0 + kk);
    As[(kk+0)*LDT+row]=av.x; As[(kk+1)*LDT+row]=av.y; As[(kk+2)*LDT+row]=av.z; As[(kk+3)*LDT+row]=av.w;
    Bs[(kk+0)*LDT+row]=bv.x; Bs[(kk+1)*LDT+row]=bv.y; Bs[(kk+2)*LDT+row]=bv.z; Bs[(kk+3)*LDT+row]=bv.w;
    __syncthreads();
    #pragma unroll
    for(int k=0;k<BK;k++){
      float4 a = *(const float4*)&As[k*LDT + 4*ty];
      float4 b = *(const float4*)&Bs[k*LDT + 4*tx];
      acc[0][0]+=a.x*b.x; acc[0][1]+=a.x*b.y; acc[0][2]+=a.x*b.z; acc[0][3]+=a.x*b.w;
      acc[1][0]+=a.y*b.x; acc[1][1]+=a.y*b.y; acc[1][2]+=a.y*b.z; acc[1][3]+=a.y*b.w;
      acc[2][0]+=a.z*b.x; acc[2][1]+=a.z*b.y; acc[2][2]+=a.z*b.z; acc[2][3]+=a.z*b.w;
      acc[3][0]+=a.w*b.x; acc[3][1]+=a.w*b.y; acc[3][2]+=a.w*b.z; acc[3][3]+=a.w*b.w;
    }
    __syncthreads();
  }
  float* Cz = C + (size_t)blockIdx.z * (size_t)gridDim.x * BM * (size_t)ldc;
  #pragma unroll
  for(int i=0;i<4;i++){
    int m = m0 + 4*ty + i;
    int n = n0 + 4*tx;
    float4 o; o.x=acc[i][0]; o.y=acc[i][1]; o.z=acc[i][2]; o.w=acc[i][3];
    if(bias0){
      o.x += bias0[n]+bias1[n];     o.y += bias0[n+1]+bias1[n+1];
      o.z += bias0[n+2]+bias1[n+2]; o.w += bias0[n+3]+bias1[n+3];
    }
    *(float4*)(Cz + (size_t)m*ldc + n) = o;
  }
}

// ---------------- FB: LSTM elementwise ----------------
__global__ __launch_bounds__(256)
void k_lstm(const float* __restrict__ xg, const float* __restrict__ gp,
            float* __restrict__ hout, float* __restrict__ c, int t)
{
  int idx = blockIdx.x*256 + threadIdx.x;   // 65536 = 128*512
  int b = idx >> 9, j = idx & 511;
  const float* xr = xg + ((size_t)b*T_ + t)*(size_t)(4*H_);
  float gi = xr[j], gf = xr[512+j], gg = xr[1024+j], go = xr[1536+j];
  #pragma unroll
  for(int s4=0;s4<4;s4++){
    const float* pr = gp + ((size_t)s4*B_ + b)*(size_t)(4*H_);
    gi += pr[j]; gf += pr[512+j]; gg += pr[1024+j]; go += pr[1536+j];
  }
  float cc = sigmoidf_(gf)*c[idx] + sigmoidf_(gi)*tanhf(gg);
  float hh = sigmoidf_(go)*tanhf(cc);
  c[idx] = cc; hout[idx] = hh;
}

// ---------------- cooperative phase A: 32x {gates GEMM -> sync -> LSTM -> sync} ----------------
// 256 blocks x 256 threads. Block g: z = g>>6 (split-K), m0=(g&1)*64, n0=((g&63)>>1)*64.
// W_hh tile (64 rows x 128 cols) cached in LDS ONCE for all 32 steps.
__global__ __launch_bounds__(256)
void k_phaseA(const float* __restrict__ xg, const float* __restrict__ h0,
              const float* __restrict__ Whh, float* __restrict__ gparts,
              float* __restrict__ h_all, float* __restrict__ c)
{
  cg::grid_group grid = cg::this_grid();
  __shared__ float Bp[128*68];   // persistent W_hh tile (34.8 KB)
  __shared__ float As[16*68];
  const int g = blockIdx.x;
  const int z = g >> 6, rem = g & 63;
  const int m0 = (rem & 1)*64, n0 = (rem >> 1)*64;
  const int tid = threadIdx.x;
  const int tx = tid & 15, ty = tid >> 4;
  const int row = tid >> 2, kq = (tid & 3)*4;

  #pragma unroll
  for(int p=0;p<8;p++){
    int kc = p*16 + kq;
    float4 bv = *(const float4*)(Whh + (size_t)(n0+row)*512 + z*128 + kc);
    Bp[(kc+0)*68+row]=bv.x; Bp[(kc+1)*68+row]=bv.y; Bp[(kc+2)*68+row]=bv.z; Bp[(kc+3)*68+row]=bv.w;
  }
  __syncthreads();

  for(int t=0;t<T_;++t){
    const float* hprev = (t==0) ? h0 : (h_all + (size_t)(t-1)*65536);
    float acc[4][4] = {};
    for(int k0=0;k0<128;k0+=16){
      float4 av = *(const float4*)(hprev + (size_t)(m0+row)*512 + z*128 + k0 + kq);
      As[(kq+0)*68+row]=av.x; As[(kq+1)*68+row]=av.y; As[(kq+2)*68+row]=av.z; As[(kq+3)*68+row]=av.w;
      __syncthreads();
      #pragma unroll
      for(int k=0;k<16;k++){
        float4 a = *(const float4*)&As[k*68 + 4*ty];
        float4 b = *(const float4*)&Bp[(k0+k)*68 + 4*tx];
        acc[0][0]+=a.x*b.x; acc[0][1]+=a.x*b.y; acc[0][2]+=a.x*b.z; acc[0][3]+=a.x*b.w;
        acc[1][0]+=a.y*b.x; acc[1][1]+=a.y*b.y; acc[1][2]+=a.y*b.z; acc[1][3]+=a.y*b.w;
        acc[2][0]+=a.z*b.x; acc[2][1]+=a.z*b.y; acc[2][2]+=a.z*b.z; acc[2][3]+=a.z*b.w;
        acc[3][0]+=a.w*b.x; acc[3][1]+=a.w*b.y; acc[3][2]+=a.w*b.z; acc[3][3]+=a.w*b.w;
      }
      __syncthreads();
    }
    float* Cz = gparts + (size_t)z*262144;
    #pragma unroll
    for(int i=0;i<4;i++){
      float4 o; o.x=acc[i][0]; o.y=acc[i][1]; o.z=acc[i][2]; o.w=acc[i][3];
      *(float4*)(Cz + (size_t)(m0+4*ty+i)*2048 + n0 + 4*tx) = o;
    }
    __threadfence();
    grid.sync();
    // LSTM elementwise: 256 blocks x 256 threads == 65536 elems
    {
      int idx = g*256 + tid;
      int bb = idx >> 9, j = idx & 511;
      const float* xr = xg + ((size_t)bb*T_ + t)*2048;
      float gi = xr[j], gf = xr[512+j], gg2 = xr[1024+j], go = xr[1536+j];
      #pragma unroll
      for(int s4=0;s4<4;s4++){
        const float* pr = gparts + ((size_t)s4*B_ + bb)*2048;
        gi += pr[j]; gf += pr[512+j]; gg2 += pr[1024+j]; go += pr[1536+j];
      }
      float cc = sigmoidf_(gf)*c[idx] + sigmoidf_(gi)*tanhf(gg2);
      float hh = sigmoidf_(go)*tanhf(cc);
      c[idx] = cc;
      (h_all + (size_t)t*65536)[idx] = hh;
    }
    __threadfence();
    grid.sync();
  }
}

// ---------------- vt+ctrl batched GEMM, 64x64 tiles, virtual cat(W_out,W_head,0) ----------------
__global__ __launch_bounds__(256)
void k_vtcat(const float* __restrict__ h,            // h_all [4096,512]
             const float* __restrict__ Wout, const float* __restrict__ bout,
             const float* __restrict__ Whead, const float* __restrict__ bhead,
             float* __restrict__ vc)                 // [4096,768]
{
  const int BK=16, LDT=68;
  __shared__ float As[BK*LDT];
  __shared__ float Bs[BK*LDT];
  const int m0 = blockIdx.x*64, n0 = blockIdx.y*64;
  const int tid = threadIdx.x;
  const int tx = tid & 15, ty = tid >> 4;
  float acc[4][4] = {};
  const int row = tid >> 2, kk = (tid & 3) * 4;
  const int nrow = n0 + row;
  const float* Bsrc = (nrow < 256) ? (Wout + (size_t)nrow*512)
                    : (nrow < 709) ? (Whead + (size_t)(nrow-256)*512) : nullptr;
  for(int k0 = 0; k0 < 512; k0 += BK){
    float4 av = *(const float4*)(h + (size_t)(m0+row)*512 + k0 + kk);
    float4 bv = make_float4(0.f,0.f,0.f,0.f);
    if(Bsrc) bv = *(const float4*)(Bsrc + k0 + kk);
    As[(kk+0)*LDT+row]=av.x; As[(kk+1)*LDT+row]=av.y; As[(kk+2)*LDT+row]=av.z; As[(kk+3)*LDT+row]=av.w;
    Bs[(kk+0)*LDT+row]=bv.x; Bs[(kk+1)*LDT+row]=bv.y; Bs[(kk+2)*LDT+row]=bv.z; Bs[(kk+3)*LDT+row]=bv.w;
    __syncthreads();
    #pragma unroll
    for(int k=0;k<BK;k++){
      float4 a = *(const float4*)&As[k*LDT + 4*ty];
      float4 b = *(const float4*)&Bs[k*LDT + 4*tx];
      acc[0][0]+=a.x*b.x; acc[0][1]+=a.x*b.y; acc[0][2]+=a.x*b.z; acc[0][3]+=a.x*b.w;
      acc[1][0]+=a.y*b.x; acc[1][1]+=a.y*b.y; acc[1][2]+=a.y*b.z; acc[1][3]+=a.y*b.w;
      acc[2][0]+=a.z*b.x; acc[2][1]+=a.z*b.y; acc[2][2]+=a.z*b.z; acc[2][3]+=a.z*b.w;
      acc[3][0]+=a.w*b.x; acc[3][1]+=a.w*b.y; acc[3][2]+=a.w*b.z; acc[3][3]+=a.w*b.w;
    }
    __syncthreads();
  }
  const int nb = n0 + 4*tx;
  float bias[4];
  #pragma unroll
  for(int j2=0;j2<4;j2++){
    int n = nb + j2;
    bias[j2] = (n < 256) ? bout[n] : (n < 709) ? bhead[n-256] : 0.f;
  }
  #pragma unroll
  for(int i=0;i<4;i++){
    float4 o; o.x=acc[i][0]+bias[0]; o.y=acc[i][1]+bias[1];
    o.z=acc[i][2]+bias[2]; o.w=acc[i][3]+bias[3];
    *(float4*)(vc + (size_t)(m0+4*ty+i)*VCS_ + nb) = o;
  }
}

// ---------------- phase B shared-memory layout (shared by coop + FB kernels) ----------------
struct __align__(16) SmemB {
  float tile[5*1024];      // logits for this block's 1024-slot chunk
  float kk[320];           // kr(256)+kw(64), tanh'd
  float coef[8];
  float er[64], ad[64];
  float coefR[4];
  float nv[512], oldrow[512];
  int   widx[8];
  float wval[8];
};

// scores role: block (b, ch in {0,1}), 512 threads, 1024 slots. Writes candW/candR/statsB.
DEV void scores_body(SmemB& sm, const float* __restrict__ memC,
                     const float* __restrict__ v, int b, int ch, int tid,
                     unsigned long long* __restrict__ candW,
                     unsigned long long* __restrict__ candR,
                     float* __restrict__ statsB)
{
  const int lane = tid & 63, wave = tid >> 6;
  const size_t memb = (size_t)b*(size_t)(S_*M_);
  if(tid < 320) sm.kk[tid] = tanhf(v[256+tid]);
  __syncthreads();
  if(tid < 5){
    float s = 0.f;
    #pragma unroll
    for(int m=0;m<64;m++){ float x = sm.kk[tid*64+m]; s += x*x; }
    float beta = softplusf_( tid<4 ? v[512+tid] : v[580] );
    sm.coef[tid] = beta / fmaxf(sqrtf(s), EPSF);
  }
  __syncthreads();
  #pragma unroll
  for(int q=0;q<2;q++){
    const int ls = q*512 + tid;                 // 0..1023
    const int gs = ch*1024 + ls;                // global slot
    const float4* row = (const float4*)(memC + memb + (size_t)gs*M_);
    float nrm=0.f,d0=0.f,d1=0.f,d2=0.f,d3=0.f,dw=0.f;
    #pragma unroll
    for(int r4=0;r4<16;r4++){
      float4 xa = row[r4];
      float av[4] = {xa.x,xa.y,xa.z,xa.w};
      #pragma unroll
      for(int j=0;j<4;j++){
        const int m = r4*4+j;
        float a = av[j];
        nrm += a*a;
        d0 += a*sm.kk[m];     d1 += a*sm.kk[64+m]; d2 += a*sm.kk[128+m];
        d3 += a*sm.kk[192+m]; dw += a*sm.kk[256+m];
      }
    }
    float inv = 1.0f / fmaxf(sqrtf(nrm), EPSF);
    sm.tile[       ls] = sm.coef[0]*d0*inv;
    sm.tile[1024 + ls] = sm.coef[1]*d1*inv;
    sm.tile[2048 + ls] = sm.coef[2]*d2*inv;
    sm.tile[3072 + ls] = sm.coef[3]*d3*inv;
    sm.tile[4096 + ls] = sm.coef[4]*dw*inv;
  }
  __syncthreads();
  if(wave < 4){
    // read head 'wave': sorted top-16 of this 1024-chunk
    const float* trow = sm.tile + wave*1024;
    unsigned long long X[16];
    #pragma unroll
    for(int j=0;j<16;j++){ int ls = lane + j*64; X[j] = packCand(trow[ls], (unsigned)(ch*1024 + ls)); }
    sort8(X); sort8(X+8); merge8x8(X);
    butterfly16(X);
    if(lane == 0){
      unsigned long long* dst = candR + (((size_t)b*2 + ch)*4 + wave)*16;
      #pragma unroll
      for(int j=0;j<16;j++) dst[j] = X[j];
    }
  } else if(wave == 4){
    // write head: sorted top-8 of this 1024-chunk
    const float* tw = sm.tile + 4*1024;
    unsigned long long X[16];
    #pragma unroll
    for(int j=0;j<16;j++){ int ls = lane + j*64; X[j] = packCand(tw[ls], (unsigned)(ch*1024 + ls)); }
    sort8(X); sort8(X+8); merge8x8(X);
    butterfly8(X, 32);                          // uses X[0..7] (lane's top-8)
    if(lane == 0){
      unsigned long long* dst = candW + ((size_t)b*2 + ch)*8;
      #pragma unroll
      for(int j=0;j<8;j++) dst[j] = X[j];
    }
  } else {
    // stats: wave 5 -> heads 0,1; wave 6 -> 2,3; wave 7 -> 4 (exact over 1024)
    int h0 = (wave==5) ? 0 : (wave==6) ? 2 : 4;
    int nh = (wave==7) ? 1 : 2;
    for(int q=0;q<nh;q++){
      int h = h0 + q;
      const float* th = sm.tile + h*1024;
      float mxl = -INFINITY;
      #pragma unroll
      for(int j=0;j<16;j++) mxl = fmaxf(mxl, th[lane + j*64]);
      float sml = 0.f;
      #pragma unroll
      for(int j=0;j<16;j++) sml += expf(th[lane + j*64] - mxl);
      float mxg = mxl;
      #pragma unroll
      for(int mask=1; mask<64; mask<<=1) mxg = fmaxf(mxg, __shfl_xor(mxg, mask, 64));
      float term = sml * expf(mxl - mxg);
      #pragma unroll
      for(int mask=1; mask<64; mask<<=1) term += __shfl_xor(term, mask, 64);
      if(lane == 0){
        float* st = statsB + (((size_t)b*2 + ch)*5 + h)*2;
        st[0] = mxg; st[1] = term;
      }
    }
  }
}

// heads role: one block per batch, 512 threads. Merges 2 chunks' cands/stats.
DEV void heads_body(SmemB& sm, float* __restrict__ memC,
                    const float* __restrict__ v, int b, int tid,
                    const unsigned long long* __restrict__ candW,
                    const unsigned long long* __restrict__ candR,
                    const float* __restrict__ statsB,
                    float* __restrict__ readsAll, int t)
{
  const int lane = tid & 63, wave = tid >> 6;
  const size_t memb = (size_t)b*(size_t)(S_*M_);
  // phase 1: parameter transforms
  if(tid < 256)      sm.kk[tid] = tanhf(v[256+tid]);           // kr
  else if(tid < 320) sm.er[tid-256] = sigmoidf_(v[581+tid-256]);
  else if(tid < 384) sm.ad[tid-320] = tanhf(v[645+tid-320]);
  __syncthreads();
  // phase 2: write-head selection (wave 0), coefR (wave 1)
  if(wave == 0){
    float mx0 = statsB[(((size_t)b*2+0)*5+4)*2], ss0 = statsB[(((size_t)b*2+0)*5+4)*2+1];
    float mx1 = statsB[(((size_t)b*2+1)*5+4)*2], ss1 = statsB[(((size_t)b*2+1)*5+4)*2+1];
    float mxw = fmaxf(mx0, mx1);
    float Zw = ss0*expf(mx0-mxw) + ss1*expf(mx1-mxw);
    unsigned long long L[8];
    L[0] = (lane < 16) ? candW[((size_t)b*2 + (lane>>3))*8 + (lane&7)] : 0ULL;
    #pragma unroll
    for(int j=1;j<8;j++) L[j] = 0ULL;
    butterfly8(L, 8);                  // merges lanes 0-15
    if(lane == 0){
      float invZ = 1.0f / Zw;
      #pragma unroll
      for(int p=0;p<8;p++){
        sm.widx[p] = (int)unpackIdx(L[p]);
        sm.wval[p] = expf(unpackVal(L[p]) - mxw) * invZ;
      }
    }
  } else if(wave == 1 && lane < 4){
    float s = 0.f;
    #pragma unroll
    for(int m=0;m<64;m++){ float x = sm.kk[lane*64+m]; s += x*x; }
    sm.coefR[lane] = softplusf_(v[512+lane]) / fmaxf(sqrtf(s), EPSF);
  }
  __syncthreads();
  // phase 3: rank-1 erase/add at the 8 write slots (512 threads = 8 x 64)
  {
    int j = tid >> 6, m = tid & 63;
    int s = sm.widx[j];
    float w = sm.wval[j];
    size_t ptr = memb + (size_t)s*M_ + m;
    float old = memC[ptr];
    sm.oldrow[j*64+m] = old;
    float x = old * (1.0f - w*sm.er[m]) + w*sm.ad[m];
    memC[ptr] = x;
    sm.nv[j*64+m] = x;
  }
  __syncthreads();
  // phases 4+5: one wave per read head
  if(wave < 4){
    const int r = wave;
    const int sW = lane & 7, g = lane >> 3;
    const float4* nv4 = (const float4*)sm.nv;
    const float4* ov4 = (const float4*)sm.oldrow;
    const float4* kr4 = (const float4*)sm.kk;
    float4 na = nv4[sW*16 + g*2], nb = nv4[sW*16 + g*2 + 1];
    float4 oa = ov4[sW*16 + g*2], ob = ov4[sW*16 + g*2 + 1];
    float4 ka = kr4[r*16  + g*2], kb = kr4[r*16  + g*2 + 1];
    float dot = na.x*ka.x + na.y*ka.y + na.z*ka.z + na.w*ka.w
              + nb.x*kb.x + nb.y*kb.y + nb.z*kb.z + nb.w*kb.w;
    float n2  = na.x*na.x + na.y*na.y + na.z*na.z + na.w*na.w
              + nb.x*nb.x + nb.y*nb.y + nb.z*nb.z + nb.w*nb.w;
    float odot= oa.x*ka.x + oa.y*ka.y + oa.z*ka.z + oa.w*ka.w
              + ob.x*kb.x + ob.y*kb.y + ob.z*kb.z + ob.w*kb.w;
    float on2 = oa.x*oa.x + oa.y*oa.y + oa.z*oa.z + oa.w*oa.w
              + ob.x*ob.x + ob.y*ob.y + ob.z*ob.z + ob.w*ob.w;
    #pragma unroll
    for(int mask=8; mask<64; mask<<=1){
      dot  += __shfl_xor(dot,  mask, 64);
      n2   += __shfl_xor(n2,   mask, 64);
      odot += __shfl_xor(odot, mask, 64);
      on2  += __shfl_xor(on2,  mask, 64);
    }
    float fixv = sm.coefR[r] * dot  / fmaxf(sqrtf(n2),  EPSF);
    float oldv = sm.coefR[r] * odot / fmaxf(sqrtf(on2), EPSF);
    int myw = sm.widx[sW];
    float mx0 = statsB[(((size_t)b*2+0)*5+r)*2], ss0 = statsB[(((size_t)b*2+0)*5+r)*2+1];
    float mx1 = statsB[(((size_t)b*2+1)*5+r)*2], ss1 = statsB[(((size_t)b*2+1)*5+r)*2+1];
    float mxp = fmaxf(mx0, mx1);
    // candidates: 32 chunk entries (invalidate written) + 8 written with new logits
    unsigned long long eA = 0ULL;
    if(lane < 32){
      int c2 = lane >> 4, rank = lane & 15;
      eA = candR[(((size_t)b*2 + c2)*4 + r)*16 + rank];
      unsigned idxA = unpackIdx(eA);
      bool kill = false;
      #pragma unroll
      for(int p=0;p<8;p++) kill = kill || (idxA == (unsigned)sm.widx[p]);
      if(kill) eA = 0ULL;
    }
    unsigned long long eB = (lane < 8) ? packCand(fixv, (unsigned)myw) : 0ULL;
    unsigned long long L[8];
    L[0] = (eA > eB) ? eA : eB;
    L[1] = (eA > eB) ? eB : eA;
    #pragma unroll
    for(int j=2;j<8;j++) L[j] = 0ULL;
    butterfly8(L, 32);                 // all lanes -> post-patch sorted top-8
    // exact denominator: Z' = Z_pre(mxS) - sum exp(old) + sum exp(new)
    float mxS = fmaxf(mxp, unpackVal(L[0]));
    float Zp = ss0*expf(mx0-mxS) + ss1*expf(mx1-mxS);
    float adj = (lane < 8) ? (expf(fixv - mxS) - expf(oldv - mxS)) : 0.f;
    #pragma unroll
    for(int mask=1; mask<64; mask<<=1) adj += __shfl_xor(adj, mask, 64);
    float invZ = 1.0f / (Zp + adj);
    float acc = 0.f;                   // lane == mem dim m
    #pragma unroll
    for(int p=0;p<8;p++){
      float w = expf(unpackVal(L[p]) - mxS) * invZ;
      int si = (int)unpackIdx(L[p]);
      acc += w * memC[memb + (size_t)si*M_ + lane];
    }
    readsAll[((size_t)b*T_ + t)*256 + r*64 + lane] = acc;
  }
}

// ---------------- cooperative phase B: 32x {scores -> sync -> heads -> sync} ----------------
// 256 blocks x 512 threads: b = blk & 127, ch = blk >> 7. Heads on blocks < 128.
__global__ __launch_bounds__(512)
void k_phaseB(float* memC, const float* vcAll,
              unsigned long long* candW, unsigned long long* candR,
              float* statsB, float* readsAll)
{
  cg::grid_group grid = cg::this_grid();
  __shared__ SmemB sm;
  const int blk = blockIdx.x;
  const int b = blk & 127, ch = blk >> 7;
  for(int t=0;t<T_;++t){
    const float* v = vcAll + ((size_t)t*B_ + b)*VCS_;
    scores_body(sm, memC, v, b, ch, threadIdx.x, candW, candR, statsB);
    __threadfence();
    grid.sync();
    if(blk < 128)
      heads_body(sm, memC, v, b, threadIdx.x, candW, candR, statsB, readsAll, t);
    __threadfence();
    grid.sync();
  }
}

// ---------------- FB (non-cooperative) phase B kernels ----------------
__global__ __launch_bounds__(512)
void k_scoresFB(const float* memC, const float* vcAll, int t,
                unsigned long long* candW, unsigned long long* candR, float* statsB)
{
  __shared__ SmemB sm;
  const int b = blockIdx.x, ch = blockIdx.y;
  const float* v = vcAll + ((size_t)t*B_ + b)*VCS_;
  scores_body(sm, memC, v, b, ch, threadIdx.x, candW, candR, statsB);
}
__global__ __launch_bounds__(512)
void k_headsFB(float* memC, const float* vcAll, int t,
               const unsigned long long* candW, const unsigned long long* candR,
               const float* statsB, float* readsAll)
{
  __shared__ SmemB sm;
  const int b = blockIdx.x;
  const float* v = vcAll + ((size_t)t*B_ + b)*VCS_;
  heads_body(sm, memC, v, b, threadIdx.x, candW, candR, statsB, readsAll, t);
}

// ---------------- final: out = reads_all @ W_rd^T + b_rd + vt ----------------
__global__ __launch_bounds__(256)
void k_outg(const float* __restrict__ A,             // reads_all [4096,256]
            const float* __restrict__ Wrd,           // [256,256]
            const float* __restrict__ brd,
            const float* __restrict__ vcAll,
            float* __restrict__ out)
{
  const int BK=16, LDT=68;
  __shared__ float As[BK*LDT];
  __shared__ float Bs[BK*LDT];
  const int m0 = blockIdx.x*64, n0 = blockIdx.y*64;
  const int tid = threadIdx.x;
  const int tx = tid & 15, ty = tid >> 4;
  float acc[4][4] = {};
  const int row = tid >> 2, kk = (tid & 3) * 4;
  for(int k0 = 0; k0 < 256; k0 += BK){
    float4 av = *(const float4*)(A   + (size_t)(m0+row)*256 + k0 + kk);
    float4 bv = *(const float4*)(Wrd + (size_t)(n0+row)*256 + k0 + kk);
    As[(kk+0)*LDT+row]=av.x; As[(kk+1)*LDT+row]=av.y; As[(kk+2)*LDT+row]=av.z; As[(kk+3)*LDT+row]=av.w;
    Bs[(kk+0)*LDT+row]=bv.x; Bs[(kk+1)*LDT+row]=bv.y; Bs[(kk+2)*LDT+row]=bv.z; Bs[(kk+3)*LDT+row]=bv.w;
    __syncthreads();
    #pragma unroll
    for(int k=0;k<BK;k++){
      float4 a = *(const float4*)&As[k*LDT + 4*ty];
      float4 b = *(const float4*)&Bs[k*LDT + 4*tx];
      acc[0][0]+=a.x*b.x; acc[0][1]+=a.x*b.y; acc[0][2]+=a.x*b.z; acc[0][3]+=a.x*b.w;
      acc[1][0]+=a.y*b.x; acc[1][1]+=a.y*b.y; acc[1][2]+=a.y*b.z; acc[1][3]+=a.y*b.w;
      acc[2][0]+=a.z*b.x; acc[2][1]+=a.z*b.y; acc[2][2]+=a.z*b.z; acc[2][3]+=a.z*b.w;
      acc[3][0]+=a.w*b.x; acc[3][1]+=a.w*b.y; acc[3][2]+=a.w*b.z; acc[3][3]+=a.w*b.w;
    }
    __syncthreads();
  }
  const int nb = n0 + 4*tx;
  float4 bb = *(const float4*)(brd + nb);
  #pragma unroll
  for(int i=0;i<4;i++){
    int m = m0 + 4*ty + i;
    int b = m >> 5, tt = m & 31;
    float4 vt = *(const float4*)(vcAll + (size_t)(tt*B_ + b)*VCS_ + nb);
    float4 o;
    o.x = acc[i][0] + bb.x + vt.x;
    o.y = acc[i][1] + bb.y + vt.y;
    o.z = acc[i][2] + bb.z + vt.z;
    o.w = acc[i][3] + bb.w + vt.w;
    *(float4*)(out + (size_t)m*256 + nb) = o;
  }
}

// ---------------- host ----------------
extern "C" void kernel_launch(void* const* d_in, const int* in_sizes, int n_in,
                              void* d_out, int out_size, void* d_ws, size_t ws_size,
                              hipStream_t stream)
{
  const float* x     = (const float*)d_in[0];
  const float* h0    = (const float*)d_in[1];
  const float* c0    = (const float*)d_in[2];
  const float* mem0  = (const float*)d_in[3];
  const float* W_ih  = (const float*)d_in[4];
  const float* W_hh  = (const float*)d_in[5];
  const float* b_ih  = (const float*)d_in[6];
  const float* b_hh  = (const float*)d_in[7];
  const float* W_out = (const float*)d_in[8];
  const float* b_out = (const float*)d_in[9];
  const float* W_rd  = (const float*)d_in[10];
  const float* b_rd  = (const float*)d_in[11];
  const float* W_head= (const float*)d_in[12];
  const float* b_head= (const float*)d_in[13];
  // d_in[14] = K (int) — fixed at 8 by the problem setup; hard-coded in heads_body.
  float* out = (float*)d_out;

  float* ws     = (float*)d_ws;
  float* memC   = ws;                    // 128*2048*64  = 16,777,216  (slot-major [B,S,M])
  float* xg     = memC   + 16777216;     // 4096*2048    =  8,388,608  (phase A; reused in B)
  float* h_all  = xg     + 8388608;      // 32*128*512   =  2,097,152
  float* c      = h_all  + 2097152;      // 128*512      =     65,536
  float* gparts = c      + 65536;        // 4*128*2048   =  1,048,576  (phase A; = reads_all in B)
  float* reads_all = gparts;             // 4096*256     =  1,048,576  (phase B)
  // phase-B overlays inside the dead xg region (8,388,608 floats):
  float* vc_all = xg;                                                 // 4096*768 = 3,145,728
  unsigned long long* candW  = (unsigned long long*)(xg + 3145728);   // 2048 u64 (4,096 f)
  unsigned long long* candR  = candW + 2048;                          // 16384 u64 (32,768 f)
  float*              statsB = (float*)(candR + 16384);               // 2,560 f
  const size_t need = (size_t)(28377088) * sizeof(float);
  if(ws_size < need) return;  // ~113.5 MB workspace (proven capacity)

  int occA = 0, occB = 0;
  hipOccupancyMaxActiveBlocksPerMultiprocessor(&occA, k_phaseA, 256, 0);
  hipOccupancyMaxActiveBlocksPerMultiprocessor(&occB, k_phaseB, 512, 0);

  hipMemcpyAsync(c, c0, 65536*sizeof(float), hipMemcpyDeviceToDevice, stream);
  hipMemcpyAsync(memC, mem0, (size_t)16777216*sizeof(float), hipMemcpyDeviceToDevice, stream);
  // xg[b*T+t, :] = x @ W_ih^T + (b_ih+b_hh)
  k_gemm64<<<dim3(64,32,1),256,0,stream>>>(x,256, W_ih,256, xg,2048, 256, b_ih,b_hh);

  // ---- phase A: LSTM recurrence ----
  bool coopA = (occA >= 1);
  if(coopA){
    const float* a0 = xg; const float* a1 = h0; const float* a2 = W_hh;
    float* a3 = gparts; float* a4 = h_all; float* a5 = c;
    void* argsA[6] = {(void*)&a0,(void*)&a1,(void*)&a2,(void*)&a3,(void*)&a4,(void*)&a5};
    if(hipLaunchCooperativeKernel((void*)k_phaseA, dim3(256), dim3(256), argsA, 0, stream) != hipSuccess)
      coopA = false;
  }
  if(!coopA){
    for(int t=0;t<T_;t++){
      const float* hprev = (t == 0) ? h0 : (h_all + (size_t)(t-1)*65536);
      k_gemm64<<<dim3(2,32,4),256,0,stream>>>(hprev,512, W_hh,512, gparts,2048, 128, nullptr,nullptr);
      k_lstm<<<256,256,0,stream>>>(xg, gparts, h_all + (size_t)t*65536, c, t);
    }
  }
  // ---- all vt+ctrl in one batched 64x64-tile GEMM ----
  k_vtcat<<<dim3(64,12),256,0,stream>>>(h_all, W_out,b_out, W_head,b_head, vc_all);

  // ---- phase B: memory loop ----
  bool coopB = (occB >= 1);
  if(coopB){
    float* p0 = memC; const float* p1 = vc_all;
    unsigned long long* p2 = candW; unsigned long long* p3 = candR;
    float* p4 = statsB; float* p5 = reads_all;
    void* argsB[6] = {(void*)&p0,(void*)&p1,(void*)&p2,(void*)&p3,(void*)&p4,(void*)&p5};
    if(hipLaunchCooperativeKernel((void*)k_phaseB, dim3(256), dim3(512), argsB, 0, stream) != hipSuccess)
      coopB = false;
  }
  if(!coopB){
    for(int t=0;t<T_;t++){
      k_scoresFB<<<dim3(128,2),512,0,stream>>>(memC, vc_all, t, candW, candR, statsB);
      k_headsFB<<<128,512,0,stream>>>(memC, vc_all, t, candW, candR, statsB, reads_all);
    }
  }
  // ---- final output GEMM: out = reads_all @ W_rd^T + b_rd + vt ----
  k_outg<<<dim3(64,4),256,0,stream>>>(reads_all, W_rd, b_rd, vc_all, out);
}

// Round 9
// 5375.544 us; speedup vs baseline: 1.7586x; 1.7586x over previous
//
#include <hip/hip_runtime.h>
#include <math.h>

#define DEV __device__ __forceinline__

static constexpr int B_ = 128, T_ = 32, H_ = 512;
static constexpr int S_ = 2048, M_ = 64, OUT_ = 256;
static constexpr int VCS_ = 768;  // vc row stride: 256 (vt) + 453 (ctrl) padded to 768
static constexpr float EPSF = 1e-8f;

DEV float sigmoidf_(float x){ return 1.0f/(1.0f+expf(-x)); }
DEV float softplusf_(float x){ return fmaxf(x,0.0f) + log1pf(expf(-fabsf(x))); }

// ---- packed candidate: (monotonic(value) << 32) | ~idx  => u64 '>' == (value desc, idx asc)
DEV unsigned long long packCand(float v, unsigned idx){
  unsigned u = __float_as_uint(v);
  unsigned m = (u & 0x80000000u) ? ~u : (u | 0x80000000u);
  return ((unsigned long long)m << 32) | (unsigned)(~idx);
}
DEV float unpackVal(unsigned long long e){
  unsigned m = (unsigned)(e >> 32);
  unsigned u = (m & 0x80000000u) ? (m & 0x7FFFFFFFu) : ~m;
  return __uint_as_float(u);
}
DEV unsigned unpackIdx(unsigned long long e){ return ~(unsigned)e; }

DEV void cswp(unsigned long long &a, unsigned long long &b){
  if(a < b){ unsigned long long t=a; a=b; b=t; }   // larger first (descending)
}
// Batcher odd-even mergesort for 8, descending
DEV void sort8(unsigned long long* L){
  cswp(L[0],L[1]); cswp(L[2],L[3]); cswp(L[4],L[5]); cswp(L[6],L[7]);
  cswp(L[0],L[2]); cswp(L[1],L[3]); cswp(L[4],L[6]); cswp(L[5],L[7]);
  cswp(L[1],L[2]); cswp(L[5],L[6]);
  cswp(L[0],L[4]); cswp(L[1],L[5]); cswp(L[2],L[6]); cswp(L[3],L[7]);
  cswp(L[2],L[4]); cswp(L[3],L[5]);
  cswp(L[1],L[2]); cswp(L[3],L[4]); cswp(L[5],L[6]);
}
// bitonic merge of 16, descending (input must be bitonic)
DEV void bmerge16(unsigned long long* C){
  #pragma unroll
  for(int i=0;i<8;i++) cswp(C[i],C[i+8]);
  #pragma unroll
  for(int g=0;g<2;g++){ int o=g*8;
    cswp(C[o+0],C[o+4]); cswp(C[o+1],C[o+5]); cswp(C[o+2],C[o+6]); cswp(C[o+3],C[o+7]); }
  #pragma unroll
  for(int g=0;g<4;g++){ int o=g*4; cswp(C[o+0],C[o+2]); cswp(C[o+1],C[o+3]); }
  #pragma unroll
  for(int g=0;g<8;g++){ int o=g*2; cswp(C[o],C[o+1]); }
}
// butterfly keep-8: each lane holds sorted-8 desc
DEV void butterfly8(unsigned long long* L, int maxMask){
  for(int mask=1; mask<=maxMask; mask<<=1){
    unsigned long long O[8], C[8];
    #pragma unroll
    for(int i=0;i<8;i++) O[i] = __shfl_xor(L[i], mask, 64);
    #pragma unroll
    for(int i=0;i<8;i++){ unsigned long long a=L[i], b=O[7-i]; C[i] = (a>b)?a:b; }
    cswp(C[0],C[4]); cswp(C[1],C[5]); cswp(C[2],C[6]); cswp(C[3],C[7]);
    cswp(C[0],C[2]); cswp(C[1],C[3]); cswp(C[4],C[6]); cswp(C[5],C[7]);
    cswp(C[0],C[1]); cswp(C[2],C[3]); cswp(C[4],C[5]); cswp(C[6],C[7]);
    #pragma unroll
    for(int i=0;i<8;i++) L[i]=C[i];
  }
}
// butterfly keep-16 over all 64 lanes (per-lane lists sorted-16 desc)
DEV void butterfly16(unsigned long long* L){
  for(int mask=1; mask<64; mask<<=1){
    unsigned long long O[16], C[16];
    #pragma unroll
    for(int i=0;i<16;i++) O[i] = __shfl_xor(L[i], mask, 64);
    #pragma unroll
    for(int i=0;i<16;i++){ unsigned long long a=L[i], b=O[15-i]; C[i] = (a>b)?a:b; }
    bmerge16(C);
    #pragma unroll
    for(int i=0;i<16;i++) L[i]=C[i];
  }
}

// ---------------- generic fp32 GEMM  C[M,N] = A[M,K] * Bm[N,K]^T ----------------
__global__ __launch_bounds__(256)
void k_gemm64(const float* __restrict__ A, int lda,
              const float* __restrict__ Bm, int ldb,
              float* __restrict__ C, int ldc,
              int kCount,
              const float* __restrict__ bias0, const float* __restrict__ bias1)
{
  const int BM=64, BN=64, BK=16, LDT=68;
  __shared__ float As[BK*LDT];
  __shared__ float Bs[BK*LDT];
  const int m0 = blockIdx.x*BM, n0 = blockIdx.y*BN;
  const int tid = threadIdx.x;
  const int tx = tid & 15, ty = tid >> 4;
  const int kStart = blockIdx.z * kCount;
  float acc[4][4] = {};
  const int row = tid >> 2, kk = (tid & 3) * 4;
  for(int k0 = kStart; k0 < kStart + kCount; k0 += BK){
    float4 av = *(const float4*)(A  + (size_t)(m0+row)*lda + k0 + kk);
    float4 bv = *(const float4*)(Bm + (size_t)(n0+row)*ldb + k0 + kk);
    As[(kk+0)*LDT+row]=av.x; As[(kk+1)*LDT+row]=av.y; As[(kk+2)*LDT+row]=av.z; As[(kk+3)*LDT+row]=av.w;
    Bs[(kk+0)*LDT+row]=bv.x; Bs[(kk+1)*LDT+row]=bv.y; Bs[(kk+2)*LDT+row]=bv.z; Bs[(kk+3)*LDT+row]=bv.w;
    __syncthreads();
    #pragma unroll
    for(int k=0;k<BK;k++){
      float4 a = *(const float4*)&As[k*LDT + 4*ty];
      float4 b = *(const float4*)&Bs[k*LDT + 4*tx];
      acc[0][0]+=a.x*b.x; acc[0][1]+=a.x*b.y; acc[0][2]+=a.x*b.z; acc[0][3]+=a.x*b.w;
      acc[1][0]+=a.y*b.x; acc[1][1]+=a.y*b.y; acc[1][2]+=a.y*b.z; acc[1][3]+=a.y*b.w;
      acc[2][0]+=a.z*b.x; acc[2][1]+=a.z*b.y; acc[2][2]+=a.z*b.z; acc[2][3]+=a.z*b.w;
      acc[3][0]+=a.w*b.x; acc[3][1]+=a.w*b.y; acc[3][2]+=a.w*b.z; acc[3][3]+=a.w*b.w;
    }
    __syncthreads();
  }
  float* Cz = C + (size_t)blockIdx.z * (size_t)gridDim.x * BM * (size_t)ldc;
  #pragma unroll
  for(int i=0;i<4;i++){
    int m = m0 + 4*ty + i;
    int n = n0 + 4*tx;
    float4 o; o.x=acc[i][0]; o.y=acc[i][1]; o.z=acc[i][2]; o.w=acc[i][3];
    if(bias0){
      o.x += bias0[n]+bias1[n];     o.y += bias0[n+1]+bias1[n+1];
      o.z += bias0[n+2]+bias1[n+2]; o.w += bias0[n+3]+bias1[n+3];
    }
    *(float4*)(Cz + (size_t)m*ldc + n) = o;
  }
}

// ---------------- phase A fused: split-K gates GEMM + last-arriver LSTM epilogue ----------------
// grid (2,32,4): m0 = bx*64 (batch-half), n0 = by*64 (gate cols), z = K-slice.
// Counter group (bx, by&7): 16 contributing blocks (4 gate regions x 4 K-slices).
// Last arriver computes LSTM for batches [bx*64,+64) x hidden [(by&7)*64,+64).
__global__ __launch_bounds__(256)
void k_gemmA(const float* __restrict__ hprev, const float* __restrict__ Whh,
             const float* __restrict__ xg, float* __restrict__ gparts,
             float* __restrict__ h_all_t, float* __restrict__ c,
             int* __restrict__ cnt, int t)
{
  const int BK=16, LDT=68;
  __shared__ float As[BK*LDT];
  __shared__ float Bs[BK*LDT];
  __shared__ int old_s;
  const int m0 = blockIdx.x*64, n0 = blockIdx.y*64;
  const int z = blockIdx.z;
  const int tid = threadIdx.x;
  const int tx = tid & 15, ty = tid >> 4;
  float acc[4][4] = {};
  const int row = tid >> 2, kq = (tid & 3) * 4;
  const int kStart = z*128;
  for(int k0 = kStart; k0 < kStart + 128; k0 += BK){
    float4 av = *(const float4*)(hprev + (size_t)(m0+row)*512 + k0 + kq);
    float4 bv = *(const float4*)(Whh   + (size_t)(n0+row)*512 + k0 + kq);
    As[(kq+0)*LDT+row]=av.x; As[(kq+1)*LDT+row]=av.y; As[(kq+2)*LDT+row]=av.z; As[(kq+3)*LDT+row]=av.w;
    Bs[(kq+0)*LDT+row]=bv.x; Bs[(kq+1)*LDT+row]=bv.y; Bs[(kq+2)*LDT+row]=bv.z; Bs[(kq+3)*LDT+row]=bv.w;
    __syncthreads();
    #pragma unroll
    for(int k=0;k<BK;k++){
      float4 a = *(const float4*)&As[k*LDT + 4*ty];
      float4 b = *(const float4*)&Bs[k*LDT + 4*tx];
      acc[0][0]+=a.x*b.x; acc[0][1]+=a.x*b.y; acc[0][2]+=a.x*b.z; acc[0][3]+=a.x*b.w;
      acc[1][0]+=a.y*b.x; acc[1][1]+=a.y*b.y; acc[1][2]+=a.y*b.z; acc[1][3]+=a.y*b.w;
      acc[2][0]+=a.z*b.x; acc[2][1]+=a.z*b.y; acc[2][2]+=a.z*b.z; acc[2][3]+=a.z*b.w;
      acc[3][0]+=a.w*b.x; acc[3][1]+=a.w*b.y; acc[3][2]+=a.w*b.z; acc[3][3]+=a.w*b.w;
    }
    __syncthreads();
  }
  float* Cz = gparts + (size_t)z*262144;
  #pragma unroll
  for(int i=0;i<4;i++){
    float4 o; o.x=acc[i][0]; o.y=acc[i][1]; o.z=acc[i][2]; o.w=acc[i][3];
    *(float4*)(Cz + (size_t)(m0+4*ty+i)*2048 + n0 + 4*tx) = o;
  }
  // release partials, count arrivals
  __threadfence();
  __syncthreads();
  const int mh = blockIdx.x, jg = blockIdx.y & 7;
  if(tid == 0) old_s = atomicAdd(&cnt[mh*8 + jg], 1);
  __syncthreads();
  if(old_s == 15){
    __threadfence();   // acquire: see other blocks' partials
    #pragma unroll
    for(int q=0;q<16;q++){
      int idx = tid + q*256;               // 0..4095 = 64 batches x 64 hidden
      int bb = mh*64 + (idx >> 6);
      int j  = jg*64 + (idx & 63);
      const float* xr = xg + ((size_t)bb*T_ + t)*2048;
      float gi = xr[j], gf = xr[512+j], gg = xr[1024+j], go = xr[1536+j];
      #pragma unroll
      for(int s4=0;s4<4;s4++){
        const float* pr = gparts + (size_t)s4*262144 + (size_t)bb*2048;
        gi += pr[j]; gf += pr[512+j]; gg += pr[1024+j]; go += pr[1536+j];
      }
      int ci = bb*512 + j;
      float cc = sigmoidf_(gf)*c[ci] + sigmoidf_(gi)*tanhf(gg);
      float hh = sigmoidf_(go)*tanhf(cc);
      c[ci] = cc; h_all_t[ci] = hh;
    }
  }
}

// ---------------- vt+ctrl batched GEMM, 64x64 tiles, virtual cat(W_out,W_head,0) ----------------
__global__ __launch_bounds__(256)
void k_vtcat(const float* __restrict__ h,            // h_all [4096,512]
             const float* __restrict__ Wout, const float* __restrict__ bout,
             const float* __restrict__ Whead, const float* __restrict__ bhead,
             float* __restrict__ vc)                 // [4096,768]
{
  const int BK=16, LDT=68;
  __shared__ float As[BK*LDT];
  __shared__ float Bs[BK*LDT];
  const int m0 = blockIdx.x*64, n0 = blockIdx.y*64;
  const int tid = threadIdx.x;
  const int tx = tid & 15, ty = tid >> 4;
  float acc[4][4] = {};
  const int row = tid >> 2, kk = (tid & 3) * 4;
  const int nrow = n0 + row;
  const float* Bsrc = (nrow < 256) ? (Wout + (size_t)nrow*512)
                    : (nrow < 709) ? (Whead + (size_t)(nrow-256)*512) : nullptr;
  for(int k0 = 0; k0 < 512; k0 += BK){
    float4 av = *(const float4*)(h + (size_t)(m0+row)*512 + k0 + kk);
    float4 bv = make_float4(0.f,0.f,0.f,0.f);
    if(Bsrc) bv = *(const float4*)(Bsrc + k0 + kk);
    As[(kk+0)*LDT+row]=av.x; As[(kk+1)*LDT+row]=av.y; As[(kk+2)*LDT+row]=av.z; As[(kk+3)*LDT+row]=av.w;
    Bs[(kk+0)*LDT+row]=bv.x; Bs[(kk+1)*LDT+row]=bv.y; Bs[(kk+2)*LDT+row]=bv.z; Bs[(kk+3)*LDT+row]=bv.w;
    __syncthreads();
    #pragma unroll
    for(int k=0;k<BK;k++){
      float4 a = *(const float4*)&As[k*LDT + 4*ty];
      float4 b = *(const float4*)&Bs[k*LDT + 4*tx];
      acc[0][0]+=a.x*b.x; acc[0][1]+=a.x*b.y; acc[0][2]+=a.x*b.z; acc[0][3]+=a.x*b.w;
      acc[1][0]+=a.y*b.x; acc[1][1]+=a.y*b.y; acc[1][2]+=a.y*b.z; acc[1][3]+=a.y*b.w;
      acc[2][0]+=a.z*b.x; acc[2][1]+=a.z*b.y; acc[2][2]+=a.z*b.z; acc[2][3]+=a.z*b.w;
      acc[3][0]+=a.w*b.x; acc[3][1]+=a.w*b.y; acc[3][2]+=a.w*b.z; acc[3][3]+=a.w*b.w;
    }
    __syncthreads();
  }
  const int nb = n0 + 4*tx;
  float bias[4];
  #pragma unroll
  for(int j2=0;j2<4;j2++){
    int n = nb + j2;
    bias[j2] = (n < 256) ? bout[n] : (n < 709) ? bhead[n-256] : 0.f;
  }
  #pragma unroll
  for(int i=0;i<4;i++){
    float4 o; o.x=acc[i][0]+bias[0]; o.y=acc[i][1]+bias[1];
    o.z=acc[i][2]+bias[2]; o.w=acc[i][3]+bias[3];
    *(float4*)(vc + (size_t)(m0+4*ty+i)*VCS_ + nb) = o;
  }
}

// ---------------- phase B fused: scores per chunk + last-arriver heads ----------------
// grid (128,4) x 512 threads. Scores (round-4 verified): 512 slots/block, per-wave
// top-16/top-8/stats -> candR/candW/statsB. Last chunk block of batch b runs heads
// (round-6 verified logic; kr/coef already in this block's LDS from the scores pass).
__global__ __launch_bounds__(512)
void k_scoresH(float* __restrict__ memC, const float* __restrict__ vcAll, int t,
               unsigned long long* __restrict__ candW,
               unsigned long long* __restrict__ candR,
               float* __restrict__ statsB,
               int* __restrict__ cnt,
               float* __restrict__ readsAll)
{
  __shared__ float kk[5*64];
  __shared__ float coef[5];
  __shared__ float tile[5*512];
  __shared__ float er[64], ad[64];
  __shared__ __align__(16) float nv[512];
  __shared__ __align__(16) float oldrow[512];
  __shared__ int   widx[8];
  __shared__ float wval[8];
  __shared__ int old_s;

  const int b = blockIdx.x, ch = blockIdx.y, tid = threadIdx.x;
  const int lane = tid & 63, wid = tid >> 6;
  const float* v = vcAll + ((size_t)t*B_ + b)*VCS_;
  const size_t memb = (size_t)b*(size_t)(S_*M_);

  if(tid < 256) kk[tid] = tanhf(v[256+tid]);           // kr (4x64)
  else if(tid < 320) kk[tid] = tanhf(v[516 + tid-256]);// kw (64)
  __syncthreads();
  if(tid < 5){
    float s = 0.f;
    #pragma unroll
    for(int m=0;m<64;m++){ float x = kk[tid*64+m]; s += x*x; }
    float beta = softplusf_( tid<4 ? v[512+tid] : v[580] );
    coef[tid] = beta / fmaxf(sqrtf(s), EPSF);
  }
  __syncthreads();

  // logits for this thread's slot
  {
    const int s = ch*512 + tid;
    const float4* row = (const float4*)(memC + memb + (size_t)s*M_);
    float nrm=0.f, d0=0.f, d1=0.f, d2=0.f, d3=0.f, dw=0.f;
    #pragma unroll
    for(int r4=0;r4<16;r4++){
      float4 xa = row[r4];
      float av[4] = {xa.x,xa.y,xa.z,xa.w};
      #pragma unroll
      for(int j=0;j<4;j++){
        const int m = r4*4+j;
        float a = av[j];
        nrm += a*a;
        d0 += a*kk[m];     d1 += a*kk[64+m]; d2 += a*kk[128+m];
        d3 += a*kk[192+m]; dw += a*kk[256+m];
      }
    }
    float inv = 1.0f / fmaxf(sqrtf(nrm), EPSF);
    tile[0*512+tid] = coef[0]*d0*inv;
    tile[1*512+tid] = coef[1]*d1*inv;
    tile[2*512+tid] = coef[2]*d2*inv;
    tile[3*512+tid] = coef[3]*d3*inv;
    tile[4*512+tid] = coef[4]*dw*inv;
  }
  __syncthreads();

  if(wid < 4){
    // read head wid: sorted top-16 of this chunk
    unsigned long long L[16];
    #pragma unroll
    for(int j=0;j<8;j++){
      int i = lane + j*64;
      L[j] = packCand(tile[wid*512 + i], (unsigned)(ch*512 + i));
    }
    sort8(L);
    #pragma unroll
    for(int j=8;j<16;j++) L[j] = 0ULL;
    butterfly16(L);
    if(lane == 0){
      unsigned long long* dst = candR + (((size_t)b*4 + ch)*4 + wid)*16;
      #pragma unroll
      for(int j=0;j<16;j++) dst[j] = L[j];
    }
  } else if(wid == 4){
    // write head: sorted top-8 of this chunk
    unsigned long long L[8];
    #pragma unroll
    for(int j=0;j<8;j++){
      int i = lane + j*64;
      L[j] = packCand(tile[4*512 + i], (unsigned)(ch*512 + i));
    }
    sort8(L);
    butterfly8(L, 32);
    if(lane == 0){
      unsigned long long* dst = candW + ((size_t)b*4 + ch)*8;
      #pragma unroll
      for(int j=0;j<8;j++) dst[j] = L[j];
    }
  } else {
    // stats waves: wid 5 -> heads 0,1; wid 6 -> heads 2,3; wid 7 -> head 4
    int h0 = (wid==5) ? 0 : (wid==6) ? 2 : 4;
    int nh = (wid==7) ? 1 : 2;
    for(int q=0;q<nh;q++){
      int h = h0 + q;
      float x[8];
      #pragma unroll
      for(int j=0;j<8;j++) x[j] = tile[h*512 + lane + j*64];
      float mx = x[0];
      #pragma unroll
      for(int j=1;j<8;j++) mx = fmaxf(mx, x[j]);
      #pragma unroll
      for(int mask=1; mask<64; mask<<=1) mx = fmaxf(mx, __shfl_xor(mx, mask, 64));
      float sm = 0.f;
      #pragma unroll
      for(int j=0;j<8;j++) sm += expf(x[j]-mx);
      #pragma unroll
      for(int mask=1; mask<64; mask<<=1) sm += __shfl_xor(sm, mask, 64);
      if(lane == 0){
        float* st = statsB + (((size_t)b*4 + ch)*5 + h)*2;
        st[0] = mx; st[1] = sm;
      }
    }
  }

  // ---- arrival protocol: release stores, count chunk blocks of this batch ----
  __threadfence();
  __syncthreads();
  if(tid == 0) old_s = atomicAdd(&cnt[b], 1);
  __syncthreads();
  if(old_s != 3) return;
  __threadfence();   // acquire: see other chunks' candW/candR/statsB

  // ================= heads (last arriver; kr==kk[0..255], coefR==coef[0..3]) =================
  const int wave = wid;
  // phase 1: er/ad transforms
  if(tid < 64) er[tid] = sigmoidf_(v[581+tid]);
  else if(tid < 128) ad[tid-64] = tanhf(v[645+tid-64]);
  __syncthreads();

  // phase 2: write-head selection (wave 0)
  if(wave == 0){
    float smx[4], ssm[4];
    #pragma unroll
    for(int c2=0;c2<4;c2++){
      const float* st = statsB + (((size_t)b*4 + c2)*5 + 4)*2;
      smx[c2] = st[0]; ssm[c2] = st[1];
    }
    float mxw = fmaxf(fmaxf(smx[0],smx[1]), fmaxf(smx[2],smx[3]));
    float Zw = ssm[0]*expf(smx[0]-mxw) + ssm[1]*expf(smx[1]-mxw)
             + ssm[2]*expf(smx[2]-mxw) + ssm[3]*expf(smx[3]-mxw);
    unsigned long long L[8];
    L[0] = (lane < 32) ? candW[((size_t)b*4 + (lane>>3))*8 + (lane&7)] : 0ULL;
    #pragma unroll
    for(int j=1;j<8;j++) L[j] = 0ULL;
    butterfly8(L, 16);                 // lanes 0-31 contain the data
    if(lane == 0){
      float invZ = 1.0f / Zw;
      #pragma unroll
      for(int p=0;p<8;p++){
        widx[p] = (int)unpackIdx(L[p]);
        wval[p] = expf(unpackVal(L[p]) - mxw) * invZ;
      }
    }
  }
  __syncthreads();

  // phase 3: rank-1 erase/add at the 8 write slots (512 threads = 8 slots x 64 dims)
  {
    int j = tid >> 6, m = tid & 63;
    int s = widx[j];
    float w = wval[j];
    size_t ptr = memb + (size_t)s*M_ + m;
    float old = memC[ptr];
    oldrow[j*64+m] = old;
    float x = old * (1.0f - w*er[m]) + w*ad[m];
    memC[ptr] = x;
    nv[j*64+m] = x;
  }
  __syncthreads();

  // phases 4+5: one wave per read head r (waves 0-3)
  if(wave < 4){
    const int r = wave;
    const int sW = lane & 7, g = lane >> 3;
    const float4* nv4 = (const float4*)nv;
    const float4* ov4 = (const float4*)oldrow;
    const float4* kr4 = (const float4*)kk;
    float4 na = nv4[sW*16 + g*2], nb = nv4[sW*16 + g*2 + 1];
    float4 oa = ov4[sW*16 + g*2], ob = ov4[sW*16 + g*2 + 1];
    float4 ka = kr4[r*16  + g*2], kb = kr4[r*16  + g*2 + 1];
    float dot = na.x*ka.x + na.y*ka.y + na.z*ka.z + na.w*ka.w
              + nb.x*kb.x + nb.y*kb.y + nb.z*kb.z + nb.w*kb.w;
    float n2  = na.x*na.x + na.y*na.y + na.z*na.z + na.w*na.w
              + nb.x*nb.x + nb.y*nb.y + nb.z*nb.z + nb.w*nb.w;
    float odot= oa.x*ka.x + oa.y*ka.y + oa.z*ka.z + oa.w*ka.w
              + ob.x*kb.x + ob.y*kb.y + ob.z*kb.z + ob.w*kb.w;
    float on2 = oa.x*oa.x + oa.y*oa.y + oa.z*oa.z + oa.w*oa.w
              + ob.x*ob.x + ob.y*ob.y + ob.z*ob.z + ob.w*ob.w;
    #pragma unroll
    for(int mask=8; mask<64; mask<<=1){
      dot  += __shfl_xor(dot,  mask, 64);
      n2   += __shfl_xor(n2,   mask, 64);
      odot += __shfl_xor(odot, mask, 64);
      on2  += __shfl_xor(on2,  mask, 64);
    }
    float fixv = coef[r] * dot  / fmaxf(sqrtf(n2),  EPSF);
    float oldv = coef[r] * odot / fmaxf(sqrtf(on2), EPSF);  // pre-patch read logit @ written slot
    int myw = widx[sW];

    // pre-patch chunk stats for this head
    float scx[4], scs[4];
    #pragma unroll
    for(int c2=0;c2<4;c2++){
      const float* st = statsB + (((size_t)b*4 + c2)*5 + r)*2;
      scx[c2] = st[0]; scs[c2] = st[1];
    }
    float mxp = fmaxf(fmaxf(scx[0],scx[1]), fmaxf(scx[2],scx[3]));

    // candidates: 64 chunk entries (invalidate written) + 8 written entries with new logits
    unsigned long long L[8];
    {
      int c2 = lane >> 4, rank = lane & 15;
      unsigned long long eA = candR[(((size_t)b*4 + c2)*4 + r)*16 + rank];
      unsigned idxA = unpackIdx(eA);
      bool kill = false;
      #pragma unroll
      for(int p=0;p<8;p++) kill = kill || (idxA == (unsigned)widx[p]);
      if(kill) eA = 0ULL;
      unsigned long long eB = (lane < 8) ? packCand(fixv, (unsigned)myw) : 0ULL;
      L[0] = (eA > eB) ? eA : eB;
      L[1] = (eA > eB) ? eB : eA;
      #pragma unroll
      for(int j=2;j<8;j++) L[j] = 0ULL;
    }
    butterfly8(L, 32);                 // all lanes -> global post-patch sorted top-8

    // exact denominator: Z' = Z_pre(mxS) - sum exp(old) + sum exp(new)
    float mxS = fmaxf(mxp, unpackVal(L[0]));
    float Zp = scs[0]*expf(scx[0]-mxS) + scs[1]*expf(scx[1]-mxS)
             + scs[2]*expf(scx[2]-mxS) + scs[3]*expf(scx[3]-mxS);
    float adj = (lane < 8) ? (expf(fixv - mxS) - expf(oldv - mxS)) : 0.f;
    #pragma unroll
    for(int mask=1; mask<64; mask<<=1) adj += __shfl_xor(adj, mask, 64);
    float invZ = 1.0f / (Zp + adj);

    float acc = 0.f;                   // lane == mem dim m
    #pragma unroll
    for(int p=0;p<8;p++){
      float w = expf(unpackVal(L[p]) - mxS) * invZ;
      int si = (int)unpackIdx(L[p]);
      acc += w * memC[memb + (size_t)si*M_ + lane];   // new mem, contiguous row
    }
    readsAll[((size_t)b*T_ + t)*256 + r*64 + lane] = acc;
  }
}

// ---------------- final: out = reads_all @ W_rd^T + b_rd + vt ----------------
__global__ __launch_bounds__(256)
void k_outg(const float* __restrict__ A,             // reads_all [4096,256]
            const float* __restrict__ Wrd,           // [256,256]
            const float* __restrict__ brd,
            const float* __restrict__ vcAll,
            float* __restrict__ out)
{
  const int BK=16, LDT=68;
  __shared__ float As[BK*LDT];
  __shared__ float Bs[BK*LDT];
  const int m0 = blockIdx.x*64, n0 = blockIdx.y*64;
  const int tid = threadIdx.x;
  const int tx = tid & 15, ty = tid >> 4;
  float acc[4][4] = {};
  const int row = tid >> 2, kk = (tid & 3) * 4;
  for(int k0 = 0; k0 < 256; k0 += BK){
    float4 av = *(const float4*)(A   + (size_t)(m0+row)*256 + k0 + kk);
    float4 bv = *(const float4*)(Wrd + (size_t)(n0+row)*256 + k0 + kk);
    As[(kk+0)*LDT+row]=av.x; As[(kk+1)*LDT+row]=av.y; As[(kk+2)*LDT+row]=av.z; As[(kk+3)*LDT+row]=av.w;
    Bs[(kk+0)*LDT+row]=bv.x; Bs[(kk+1)*LDT+row]=bv.y; Bs[(kk+2)*LDT+row]=bv.z; Bs[(kk+3)*LDT+row]=bv.w;
    __syncthreads();
    #pragma unroll
    for(int k=0;k<BK;k++){
      float4 a = *(const float4*)&As[k*LDT + 4*ty];
      float4 b = *(const float4*)&Bs[k*LDT + 4*tx];
      acc[0][0]+=a.x*b.x; acc[0][1]+=a.x*b.y; acc[0][2]+=a.x*b.z; acc[0][3]+=a.x*b.w;
      acc[1][0]+=a.y*b.x; acc[1][1]+=a.y*b.y; acc[1][2]+=a.y*b.z; acc[1][3]+=a.y*b.w;
      acc[2][0]+=a.z*b.x; acc[2][1]+=a.z*b.y; acc[2][2]+=a.z*b.z; acc[2][3]+=a.z*b.w;
      acc[3][0]+=a.w*b.x; acc[3][1]+=a.w*b.y; acc[3][2]+=a.w*b.z; acc[3][3]+=a.w*b.w;
    }
    __syncthreads();
  }
  const int nb = n0 + 4*tx;
  float4 bb = *(const float4*)(brd + nb);
  #pragma unroll
  for(int i=0;i<4;i++){
    int m = m0 + 4*ty + i;
    int b = m >> 5, tt = m & 31;
    float4 vt = *(const float4*)(vcAll + (size_t)(tt*B_ + b)*VCS_ + nb);
    float4 o;
    o.x = acc[i][0] + bb.x + vt.x;
    o.y = acc[i][1] + bb.y + vt.y;
    o.z = acc[i][2] + bb.z + vt.z;
    o.w = acc[i][3] + bb.w + vt.w;
    *(float4*)(out + (size_t)m*256 + nb) = o;
  }
}

// ---------------- host ----------------
extern "C" void kernel_launch(void* const* d_in, const int* in_sizes, int n_in,
                              void* d_out, int out_size, void* d_ws, size_t ws_size,
                              hipStream_t stream)
{
  const float* x     = (const float*)d_in[0];
  const float* h0    = (const float*)d_in[1];
  const float* c0    = (const float*)d_in[2];
  const float* mem0  = (const float*)d_in[3];
  const float* W_ih  = (const float*)d_in[4];
  const float* W_hh  = (const float*)d_in[5];
  const float* b_ih  = (const float*)d_in[6];
  const float* b_hh  = (const float*)d_in[7];
  const float* W_out = (const float*)d_in[8];
  const float* b_out = (const float*)d_in[9];
  const float* W_rd  = (const float*)d_in[10];
  const float* b_rd  = (const float*)d_in[11];
  const float* W_head= (const float*)d_in[12];
  const float* b_head= (const float*)d_in[13];
  // d_in[14] = K (int) — fixed at 8 by the problem setup; hard-coded in k_scoresH.
  float* out = (float*)d_out;

  float* ws     = (float*)d_ws;
  float* memC   = ws;                    // 128*2048*64  = 16,777,216  (slot-major [B,S,M])
  float* xg     = memC   + 16777216;     // 4096*2048    =  8,388,608  (phase A; reused in B)
  float* h_all  = xg     + 8388608;      // 32*128*512   =  2,097,152
  float* c      = h_all  + 2097152;      // 128*512      =     65,536
  float* gparts = c      + 65536;        // 4*128*2048   =  1,048,576  (phase A; = reads_all in B)
  float* reads_all = gparts;             // 4096*256     =  1,048,576  (phase B)
  // phase-B overlays inside the dead xg region (8,388,608 floats):
  float* vc_all = xg;                                                 // 4096*768 = 3,145,728
  unsigned long long* candW  = (unsigned long long*)(xg + 3145728);   // 4096 u64 (8,192 f)
  unsigned long long* candR  = candW + 4096;                          // 32768 u64 (65,536 f)
  float*              statsB = (float*)(candR + 32768);               // 5,120 f
  // arrival counters (dedicated region, zeroed once per launch):
  int* cntA = (int*)(ws + 28377088);     // 32*16  = 512 ints
  int* cntB = cntA + 512;                // 32*128 = 4096 ints
  const size_t need = (size_t)(28385280) * sizeof(float);
  if(ws_size < need) return;  // ~113.5 MB workspace (<= round-4 proven capacity)

  hipMemsetAsync(cntA, 0, 4608*sizeof(int), stream);
  hipMemcpyAsync(c, c0, 65536*sizeof(float), hipMemcpyDeviceToDevice, stream);
  hipMemcpyAsync(memC, mem0, (size_t)16777216*sizeof(float), hipMemcpyDeviceToDevice, stream);
  // xg[b*T+t, :] = x @ W_ih^T + (b_ih+b_hh)
  k_gemm64<<<dim3(64,32,1),256,0,stream>>>(x,256, W_ih,256, xg,2048, 256, b_ih,b_hh);

  // ---- phase A: fused gates GEMM + last-arriver LSTM, one launch per step ----
  for(int t=0;t<T_;t++){
    const float* hprev = (t == 0) ? h0 : (h_all + (size_t)(t-1)*65536);
    k_gemmA<<<dim3(2,32,4),256,0,stream>>>(hprev, W_hh, xg, gparts,
                                           h_all + (size_t)t*65536, c, cntA + t*16, t);
  }
  // ---- all vt+ctrl in one batched 64x64-tile GEMM ----
  k_vtcat<<<dim3(64,12),256,0,stream>>>(h_all, W_out,b_out, W_head,b_head, vc_all);

  // ---- phase B: fused scores + last-arriver heads, one launch per step ----
  for(int t=0;t<T_;t++){
    k_scoresH<<<dim3(128,4),512,0,stream>>>(memC, vc_all, t, candW, candR, statsB,
                                            cntB + t*128, reads_all);
  }
  // ---- final output GEMM: out = reads_all @ W_rd^T + b_rd + vt ----
  k_outg<<<dim3(64,4),256,0,stream>>>(reads_all, W_rd, b_rd, vc_all, out);
}

// Round 10
// 1730.871 us; speedup vs baseline: 5.4615x; 3.1057x over previous
//
#include <hip/hip_runtime.h>
#include <math.h>

#define DEV __device__ __forceinline__

static constexpr int B_ = 128, T_ = 32, H_ = 512;
static constexpr int S_ = 2048, M_ = 64, OUT_ = 256;
static constexpr int VCS_ = 768;  // vc row stride: 256 (vt) + 453 (ctrl) padded to 768
static constexpr float EPSF = 1e-8f;

DEV float sigmoidf_(float x){ return 1.0f/(1.0f+expf(-x)); }
DEV float softplusf_(float x){ return fmaxf(x,0.0f) + log1pf(expf(-fabsf(x))); }

// ---- packed candidate: (monotonic(value) << 32) | ~idx  => u64 '>' == (value desc, idx asc)
DEV unsigned long long packCand(float v, unsigned idx){
  unsigned u = __float_as_uint(v);
  unsigned m = (u & 0x80000000u) ? ~u : (u | 0x80000000u);
  return ((unsigned long long)m << 32) | (unsigned)(~idx);
}
DEV float unpackVal(unsigned long long e){
  unsigned m = (unsigned)(e >> 32);
  unsigned u = (m & 0x80000000u) ? (m & 0x7FFFFFFFu) : ~m;
  return __uint_as_float(u);
}
DEV unsigned unpackIdx(unsigned long long e){ return ~(unsigned)e; }

DEV void cswp(unsigned long long &a, unsigned long long &b){
  if(a < b){ unsigned long long t=a; a=b; b=t; }   // larger first (descending)
}
// Batcher odd-even mergesort for 8, descending
DEV void sort8(unsigned long long* L){
  cswp(L[0],L[1]); cswp(L[2],L[3]); cswp(L[4],L[5]); cswp(L[6],L[7]);
  cswp(L[0],L[2]); cswp(L[1],L[3]); cswp(L[4],L[6]); cswp(L[5],L[7]);
  cswp(L[1],L[2]); cswp(L[5],L[6]);
  cswp(L[0],L[4]); cswp(L[1],L[5]); cswp(L[2],L[6]); cswp(L[3],L[7]);
  cswp(L[2],L[4]); cswp(L[3],L[5]);
  cswp(L[1],L[2]); cswp(L[3],L[4]); cswp(L[5],L[6]);
}
// bitonic merge of 16, descending (input must be bitonic)
DEV void bmerge16(unsigned long long* C){
  #pragma unroll
  for(int i=0;i<8;i++) cswp(C[i],C[i+8]);
  #pragma unroll
  for(int g=0;g<2;g++){ int o=g*8;
    cswp(C[o+0],C[o+4]); cswp(C[o+1],C[o+5]); cswp(C[o+2],C[o+6]); cswp(C[o+3],C[o+7]); }
  #pragma unroll
  for(int g=0;g<4;g++){ int o=g*4; cswp(C[o+0],C[o+2]); cswp(C[o+1],C[o+3]); }
  #pragma unroll
  for(int g=0;g<8;g++){ int o=g*2; cswp(C[o],C[o+1]); }
}
// butterfly keep-8: each lane holds sorted-8 desc
DEV void butterfly8(unsigned long long* L, int maxMask){
  for(int mask=1; mask<=maxMask; mask<<=1){
    unsigned long long O[8], C[8];
    #pragma unroll
    for(int i=0;i<8;i++) O[i] = __shfl_xor(L[i], mask, 64);
    #pragma unroll
    for(int i=0;i<8;i++){ unsigned long long a=L[i], b=O[7-i]; C[i] = (a>b)?a:b; }
    cswp(C[0],C[4]); cswp(C[1],C[5]); cswp(C[2],C[6]); cswp(C[3],C[7]);
    cswp(C[0],C[2]); cswp(C[1],C[3]); cswp(C[4],C[6]); cswp(C[5],C[7]);
    cswp(C[0],C[1]); cswp(C[2],C[3]); cswp(C[4],C[5]); cswp(C[6],C[7]);
    #pragma unroll
    for(int i=0;i<8;i++) L[i]=C[i];
  }
}
// butterfly keep-16 over all 64 lanes (per-lane lists sorted-16 desc)
DEV void butterfly16(unsigned long long* L){
  for(int mask=1; mask<64; mask<<=1){
    unsigned long long O[16], C[16];
    #pragma unroll
    for(int i=0;i<16;i++) O[i] = __shfl_xor(L[i], mask, 64);
    #pragma unroll
    for(int i=0;i<16;i++){ unsigned long long a=L[i], b=O[15-i]; C[i] = (a>b)?a:b; }
    bmerge16(C);
    #pragma unroll
    for(int i=0;i<16;i++) L[i]=C[i];
  }
}

// ---------------- generic fp32 GEMM  C[M,N] = A[M,K] * Bm[N,K]^T ----------------
__global__ __launch_bounds__(256)
void k_gemm64(const float* __restrict__ A, int lda,
              const float* __restrict__ Bm, int ldb,
              float* __restrict__ C, int ldc,
              int kCount,
              const float* __restrict__ bias0, const float* __restrict__ bias1)
{
  const int BM=64, BN=64, BK=16, LDT=68;
  __shared__ float As[BK*LDT];
  __shared__ float Bs[BK*LDT];
  const int m0 = blockIdx.x*BM, n0 = blockIdx.y*BN;
  const int tid = threadIdx.x;
  const int tx = tid & 15, ty = tid >> 4;
  const int kStart = blockIdx.z * kCount;
  float acc[4][4] = {};
  const int row = tid >> 2, kk = (tid & 3) * 4;
  for(int k0 = kStart; k0 < kStart + kCount; k0 += BK){
    float4 av = *(const float4*)(A  + (size_t)(m0+row)*lda + k0 + kk);
    float4 bv = *(const float4*)(Bm + (size_t)(n0+row)*ldb + k0 + kk);
    As[(kk+0)*LDT+row]=av.x; As[(kk+1)*LDT+row]=av.y; As[(kk+2)*LDT+row]=av.z; As[(kk+3)*LDT+row]=av.w;
    Bs[(kk+0)*LDT+row]=bv.x; Bs[(kk+1)*LDT+row]=bv.y; Bs[(kk+2)*LDT+row]=bv.z; Bs[(kk+3)*LDT+row]=bv.w;
    __syncthreads();
    #pragma unroll
    for(int k=0;k<BK;k++){
      float4 a = *(const float4*)&As[k*LDT + 4*ty];
      float4 b = *(const float4*)&Bs[k*LDT + 4*tx];
      acc[0][0]+=a.x*b.x; acc[0][1]+=a.x*b.y; acc[0][2]+=a.x*b.z; acc[0][3]+=a.x*b.w;
      acc[1][0]+=a.y*b.x; acc[1][1]+=a.y*b.y; acc[1][2]+=a.y*b.z; acc[1][3]+=a.y*b.w;
      acc[2][0]+=a.z*b.x; acc[2][1]+=a.z*b.y; acc[2][2]+=a.z*b.z; acc[2][3]+=a.z*b.w;
      acc[3][0]+=a.w*b.x; acc[3][1]+=a.w*b.y; acc[3][2]+=a.w*b.z; acc[3][3]+=a.w*b.w;
    }
    __syncthreads();
  }
  float* Cz = C + (size_t)blockIdx.z * (size_t)gridDim.x * BM * (size_t)ldc;
  #pragma unroll
  for(int i=0;i<4;i++){
    int m = m0 + 4*ty + i;
    int n = n0 + 4*tx;
    float4 o; o.x=acc[i][0]; o.y=acc[i][1]; o.z=acc[i][2]; o.w=acc[i][3];
    if(bias0){
      o.x += bias0[n]+bias1[n];     o.y += bias0[n+1]+bias1[n+1];
      o.z += bias0[n+2]+bias1[n+2]; o.w += bias0[n+3]+bias1[n+3];
    }
    *(float4*)(Cz + (size_t)m*ldc + n) = o;
  }
}

// ---------------- phase A: LSTM elementwise (writes h into h_all slice) ----------------
__global__ __launch_bounds__(256)
void k_lstm(const float* __restrict__ xg, const float* __restrict__ gp,
            float* __restrict__ hout, float* __restrict__ c, int t)
{
  int idx = blockIdx.x*256 + threadIdx.x;   // 65536 = 128*512
  int b = idx >> 9, j = idx & 511;
  const float* xr = xg + ((size_t)b*T_ + t)*(size_t)(4*H_);
  float gi = xr[j], gf = xr[512+j], gg = xr[1024+j], go = xr[1536+j];
  #pragma unroll
  for(int s4=0;s4<4;s4++){
    const float* pr = gp + ((size_t)s4*B_ + b)*(size_t)(4*H_);
    gi += pr[j]; gf += pr[512+j]; gg += pr[1024+j]; go += pr[1536+j];
  }
  float cc = sigmoidf_(gf)*c[idx] + sigmoidf_(gi)*tanhf(gg);
  float hh = sigmoidf_(go)*tanhf(cc);
  c[idx] = cc; hout[idx] = hh;
}

// ---------------- vt+ctrl batched GEMM, 64x64 tiles, virtual cat(W_out,W_head,0) ----------------
__global__ __launch_bounds__(256)
void k_vtcat(const float* __restrict__ h,            // h_all [4096,512]
             const float* __restrict__ Wout, const float* __restrict__ bout,
             const float* __restrict__ Whead, const float* __restrict__ bhead,
             float* __restrict__ vc)                 // [4096,768]
{
  const int BK=16, LDT=68;
  __shared__ float As[BK*LDT];
  __shared__ float Bs[BK*LDT];
  const int m0 = blockIdx.x*64, n0 = blockIdx.y*64;
  const int tid = threadIdx.x;
  const int tx = tid & 15, ty = tid >> 4;
  float acc[4][4] = {};
  const int row = tid >> 2, kk = (tid & 3) * 4;
  const int nrow = n0 + row;
  const float* Bsrc = (nrow < 256) ? (Wout + (size_t)nrow*512)
                    : (nrow < 709) ? (Whead + (size_t)(nrow-256)*512) : nullptr;
  for(int k0 = 0; k0 < 512; k0 += BK){
    float4 av = *(const float4*)(h + (size_t)(m0+row)*512 + k0 + kk);
    float4 bv = make_float4(0.f,0.f,0.f,0.f);
    if(Bsrc) bv = *(const float4*)(Bsrc + k0 + kk);
    As[(kk+0)*LDT+row]=av.x; As[(kk+1)*LDT+row]=av.y; As[(kk+2)*LDT+row]=av.z; As[(kk+3)*LDT+row]=av.w;
    Bs[(kk+0)*LDT+row]=bv.x; Bs[(kk+1)*LDT+row]=bv.y; Bs[(kk+2)*LDT+row]=bv.z; Bs[(kk+3)*LDT+row]=bv.w;
    __syncthreads();
    #pragma unroll
    for(int k=0;k<BK;k++){
      float4 a = *(const float4*)&As[k*LDT + 4*ty];
      float4 b = *(const float4*)&Bs[k*LDT + 4*tx];
      acc[0][0]+=a.x*b.x; acc[0][1]+=a.x*b.y; acc[0][2]+=a.x*b.z; acc[0][3]+=a.x*b.w;
      acc[1][0]+=a.y*b.x; acc[1][1]+=a.y*b.y; acc[1][2]+=a.y*b.z; acc[1][3]+=a.y*b.w;
      acc[2][0]+=a.z*b.x; acc[2][1]+=a.z*b.y; acc[2][2]+=a.z*b.z; acc[2][3]+=a.z*b.w;
      acc[3][0]+=a.w*b.x; acc[3][1]+=a.w*b.y; acc[3][2]+=a.w*b.z; acc[3][3]+=a.w*b.w;
    }
    __syncthreads();
  }
  const int nb = n0 + 4*tx;
  float bias[4];
  #pragma unroll
  for(int j2=0;j2<4;j2++){
    int n = nb + j2;
    bias[j2] = (n < 256) ? bout[n] : (n < 709) ? bhead[n-256] : 0.f;
  }
  #pragma unroll
  for(int i=0;i<4;i++){
    float4 o; o.x=acc[i][0]+bias[0]; o.y=acc[i][1]+bias[1];
    o.z=acc[i][2]+bias[2]; o.w=acc[i][3]+bias[3];
    *(float4*)(vc + (size_t)(m0+4*ty+i)*VCS_ + nb) = o;
  }
}

// ---------------- phase B: logits + per-chunk stats + per-chunk topk candidates ----------------
// grid (128, 4), 512 threads (8 waves). One slot per thread; then per-wave tasks:
// waves 0-3: sorted top-16 candidates for read heads 0-3; wave 4: sorted top-8 for write head;
// waves 5-7: (max, sum-exp) stats for heads {0,1},{2,3},{4}. No global logit store.
__global__ __launch_bounds__(512,4)
void k_scores(const float* __restrict__ memC, const float* __restrict__ vcAll, int t,
              unsigned long long* __restrict__ candW,
              unsigned long long* __restrict__ candR,
              float* __restrict__ statsB)
{
  __shared__ float kk[5*64];
  __shared__ float coef[5];
  __shared__ float tile[5*512];
  const int b = blockIdx.x, ch = blockIdx.y, tid = threadIdx.x;
  const int lane = tid & 63, wid = tid >> 6;
  const float* v = vcAll + ((size_t)t*B_ + b)*VCS_;
  if(tid < 256) kk[tid] = tanhf(v[256+tid]);           // kr (4x64)
  else if(tid < 320) kk[tid] = tanhf(v[516 + tid-256]);// kw (64)
  __syncthreads();
  if(tid < 5){
    float s = 0.f;
    #pragma unroll
    for(int m=0;m<64;m++){ float x = kk[tid*64+m]; s += x*x; }
    float beta = softplusf_( tid<4 ? v[512+tid] : v[580] );
    coef[tid] = beta / fmaxf(sqrtf(s), EPSF);
  }
  __syncthreads();

  // logits for this thread's slot
  {
    const int s = ch*512 + tid;
    const float4* row = (const float4*)(memC + ((size_t)b*S_ + s)*M_);
    float nrm=0.f, d0=0.f, d1=0.f, d2=0.f, d3=0.f, dw=0.f;
    #pragma unroll
    for(int r4=0;r4<16;r4++){
      float4 xa = row[r4];
      float av[4] = {xa.x,xa.y,xa.z,xa.w};
      #pragma unroll
      for(int j=0;j<4;j++){
        const int m = r4*4+j;
        float a = av[j];
        nrm += a*a;
        d0 += a*kk[m];     d1 += a*kk[64+m]; d2 += a*kk[128+m];
        d3 += a*kk[192+m]; dw += a*kk[256+m];
      }
    }
    float inv = 1.0f / fmaxf(sqrtf(nrm), EPSF);
    tile[0*512+tid] = coef[0]*d0*inv;
    tile[1*512+tid] = coef[1]*d1*inv;
    tile[2*512+tid] = coef[2]*d2*inv;
    tile[3*512+tid] = coef[3]*d3*inv;
    tile[4*512+tid] = coef[4]*dw*inv;
  }
  __syncthreads();

  if(wid < 4){
    // read head wid: sorted top-16 of this chunk
    unsigned long long L[16];
    #pragma unroll
    for(int j=0;j<8;j++){
      int i = lane + j*64;
      L[j] = packCand(tile[wid*512 + i], (unsigned)(ch*512 + i));
    }
    sort8(L);
    #pragma unroll
    for(int j=8;j<16;j++) L[j] = 0ULL;
    butterfly16(L);
    if(lane == 0){
      unsigned long long* dst = candR + (((size_t)b*4 + ch)*4 + wid)*16;
      #pragma unroll
      for(int j=0;j<16;j++) dst[j] = L[j];
    }
  } else if(wid == 4){
    // write head: sorted top-8 of this chunk
    unsigned long long L[8];
    #pragma unroll
    for(int j=0;j<8;j++){
      int i = lane + j*64;
      L[j] = packCand(tile[4*512 + i], (unsigned)(ch*512 + i));
    }
    sort8(L);
    butterfly8(L, 32);
    if(lane == 0){
      unsigned long long* dst = candW + ((size_t)b*4 + ch)*8;
      #pragma unroll
      for(int j=0;j<8;j++) dst[j] = L[j];
    }
  } else {
    // stats waves: wid 5 -> heads 0,1; wid 6 -> heads 2,3; wid 7 -> head 4
    int h0 = (wid==5) ? 0 : (wid==6) ? 2 : 4;
    int nh = (wid==7) ? 1 : 2;
    for(int q=0;q<nh;q++){
      int h = h0 + q;
      float x[8];
      #pragma unroll
      for(int j=0;j<8;j++) x[j] = tile[h*512 + lane + j*64];
      float mx = x[0];
      #pragma unroll
      for(int j=1;j<8;j++) mx = fmaxf(mx, x[j]);
      #pragma unroll
      for(int mask=1; mask<64; mask<<=1) mx = fmaxf(mx, __shfl_xor(mx, mask, 64));
      float sm = 0.f;
      #pragma unroll
      for(int j=0;j<8;j++) sm += expf(x[j]-mx);
      #pragma unroll
      for(int mask=1; mask<64; mask<<=1) sm += __shfl_xor(sm, mask, 64);
      if(lane == 0){
        float* st = statsB + (((size_t)b*4 + ch)*5 + h)*2;
        st[0] = mx; st[1] = sm;
      }
    }
  }
}

// ---------------- phase B: write head + mem update + read heads (reads -> global) ----------------
__global__ __launch_bounds__(256)
void k_heads(float* __restrict__ memC,
             const float* __restrict__ vcAll,
             const unsigned long long* __restrict__ candW,
             const unsigned long long* __restrict__ candR,
             const float* __restrict__ statsB,
             float* __restrict__ readsAll, int t)
{
  __shared__ __align__(16) float kr[256];
  __shared__ float er[64], ad[64];
  __shared__ float coefR[4];
  __shared__ __align__(16) float nv[512];
  __shared__ __align__(16) float oldrow[512];
  __shared__ int   widx[8];
  __shared__ float wval[8];

  const int b = blockIdx.x, tid = threadIdx.x;
  const int lane = tid & 63, wave = tid >> 6;
  const float* v = vcAll + ((size_t)t*B_ + b)*VCS_;
  const size_t memb = (size_t)b*(size_t)S_*M_;

  // phase 1: parameter transforms
  kr[tid] = tanhf(v[256+tid]);
  if(tid < 64){ er[tid] = sigmoidf_(v[581+tid]); ad[tid] = tanhf(v[645+tid]); }
  __syncthreads();

  // phase 2: write-head selection (wave 0), coefR (wave 1)
  if(wave == 0){
    float smx[4], ssm[4];
    #pragma unroll
    for(int c=0;c<4;c++){
      const float* st = statsB + (((size_t)b*4 + c)*5 + 4)*2;
      smx[c] = st[0]; ssm[c] = st[1];
    }
    float mxw = fmaxf(fmaxf(smx[0],smx[1]), fmaxf(smx[2],smx[3]));
    float Zw = ssm[0]*expf(smx[0]-mxw) + ssm[1]*expf(smx[1]-mxw)
             + ssm[2]*expf(smx[2]-mxw) + ssm[3]*expf(smx[3]-mxw);
    unsigned long long L[8];
    L[0] = (lane < 32) ? candW[((size_t)b*4 + (lane>>3))*8 + (lane&7)] : 0ULL;
    #pragma unroll
    for(int j=1;j<8;j++) L[j] = 0ULL;
    butterfly8(L, 16);                 // lanes 0-31 contain the data; 5 steps suffice
    if(lane == 0){
      float invZ = 1.0f / Zw;
      #pragma unroll
      for(int p=0;p<8;p++){
        widx[p] = (int)unpackIdx(L[p]);
        wval[p] = expf(unpackVal(L[p]) - mxw) * invZ;
      }
    }
  } else if(wave == 1 && lane < 4){
    float s = 0.f;
    #pragma unroll
    for(int m=0;m<64;m++){ float x = kr[lane*64+m]; s += x*x; }
    coefR[lane] = softplusf_(v[512+lane]) / fmaxf(sqrtf(s), EPSF);
  }
  __syncthreads();

  // phase 3: rank-1 erase/add at the 8 write slots; stash OLD rows for the Z adjustment
  #pragma unroll
  for(int p=0;p<2;p++){
    int idx = tid + p*256;              // 512 = 8 slots x 64 dims
    int j = idx >> 6, m = idx & 63;
    int s = widx[j];
    float w = wval[j];
    size_t ptr = memb + (size_t)s*M_ + m;
    float old = memC[ptr];
    oldrow[j*64+m] = old;
    float x = old * (1.0f - w*er[m]) + w*ad[m];
    memC[ptr] = x;
    nv[j*64+m] = x;
  }
  __syncthreads();

  // phases 4+5 fused, one wave per read head r
  {
    const int r = wave;
    const int sW = lane & 7, g = lane >> 3;
    const float4* nv4 = (const float4*)nv;
    const float4* ov4 = (const float4*)oldrow;
    const float4* kr4 = (const float4*)kr;
    float4 na = nv4[sW*16 + g*2], nb = nv4[sW*16 + g*2 + 1];
    float4 oa = ov4[sW*16 + g*2], ob = ov4[sW*16 + g*2 + 1];
    float4 ka = kr4[r*16  + g*2], kb = kr4[r*16  + g*2 + 1];
    float dot = na.x*ka.x + na.y*ka.y + na.z*ka.z + na.w*ka.w
              + nb.x*kb.x + nb.y*kb.y + nb.z*kb.z + nb.w*kb.w;
    float n2  = na.x*na.x + na.y*na.y + na.z*na.z + na.w*na.w
              + nb.x*nb.x + nb.y*nb.y + nb.z*nb.z + nb.w*nb.w;
    float odot= oa.x*ka.x + oa.y*ka.y + oa.z*ka.z + oa.w*ka.w
              + ob.x*kb.x + ob.y*kb.y + ob.z*kb.z + ob.w*kb.w;
    float on2 = oa.x*oa.x + oa.y*oa.y + oa.z*oa.z + oa.w*oa.w
              + ob.x*ob.x + ob.y*ob.y + ob.z*ob.z + ob.w*ob.w;
    #pragma unroll
    for(int mask=8; mask<64; mask<<=1){
      dot  += __shfl_xor(dot,  mask, 64);
      n2   += __shfl_xor(n2,   mask, 64);
      odot += __shfl_xor(odot, mask, 64);
      on2  += __shfl_xor(on2,  mask, 64);
    }
    float fixv = coefR[r] * dot  / fmaxf(sqrtf(n2),  EPSF);
    float oldv = coefR[r] * odot / fmaxf(sqrtf(on2), EPSF);  // pre-patch read logit @ written slot
    int myw = widx[sW];

    // pre-patch chunk stats for this head
    float scx[4], scs[4];
    #pragma unroll
    for(int c=0;c<4;c++){
      const float* st = statsB + (((size_t)b*4 + c)*5 + r)*2;
      scx[c] = st[0]; scs[c] = st[1];
    }
    float mxp = fmaxf(fmaxf(scx[0],scx[1]), fmaxf(scx[2],scx[3]));

    // candidates: 64 chunk entries (invalidate written) + 8 written entries with new logits
    unsigned long long L[8];
    {
      int c = lane >> 4, rank = lane & 15;
      unsigned long long eA = candR[(((size_t)b*4 + c)*4 + r)*16 + rank];
      unsigned idxA = unpackIdx(eA);
      bool kill = false;
      #pragma unroll
      for(int p=0;p<8;p++) kill = kill || (idxA == (unsigned)widx[p]);
      if(kill) eA = 0ULL;
      unsigned long long eB = (lane < 8) ? packCand(fixv, (unsigned)myw) : 0ULL;
      L[0] = (eA > eB) ? eA : eB;
      L[1] = (eA > eB) ? eB : eA;
      #pragma unroll
      for(int j=2;j<8;j++) L[j] = 0ULL;
    }
    butterfly8(L, 32);                 // all lanes -> global post-patch sorted top-8

    // exact denominator: Z' = Z_pre(mxS) - sum exp(old) + sum exp(new)
    float mxS = fmaxf(mxp, unpackVal(L[0]));
    float Zp = scs[0]*expf(scx[0]-mxS) + scs[1]*expf(scx[1]-mxS)
             + scs[2]*expf(scx[2]-mxS) + scs[3]*expf(scx[3]-mxS);
    float adj = (lane < 8) ? (expf(fixv - mxS) - expf(oldv - mxS)) : 0.f;
    #pragma unroll
    for(int mask=1; mask<64; mask<<=1) adj += __shfl_xor(adj, mask, 64);
    float invZ = 1.0f / (Zp + adj);

    float acc = 0.f;                   // lane == mem dim m
    #pragma unroll
    for(int p=0;p<8;p++){
      float w = expf(unpackVal(L[p]) - mxS) * invZ;
      int si = (int)unpackIdx(L[p]);
      acc += w * memC[memb + (size_t)si*M_ + lane];   // new mem, contiguous row
    }
    readsAll[((size_t)b*T_ + t)*256 + r*64 + lane] = acc;
  }
}

// ---------------- final: out = reads_all @ W_rd^T + b_rd + vt ----------------
__global__ __launch_bounds__(256)
void k_outg(const float* __restrict__ A,             // reads_all [4096,256]
            const float* __restrict__ Wrd,           // [256,256]
            const float* __restrict__ brd,
            const float* __restrict__ vcAll,
            float* __restrict__ out)
{
  const int BK=16, LDT=68;
  __shared__ float As[BK*LDT];
  __shared__ float Bs[BK*LDT];
  const int m0 = blockIdx.x*64, n0 = blockIdx.y*64;
  const int tid = threadIdx.x;
  const int tx = tid & 15, ty = tid >> 4;
  float acc[4][4] = {};
  const int row = tid >> 2, kk = (tid & 3) * 4;
  for(int k0 = 0; k0 < 256; k0 += BK){
    float4 av = *(const float4*)(A   + (size_t)(m0+row)*256 + k0 + kk);
    float4 bv = *(const float4*)(Wrd + (size_t)(n0+row)*256 + k0 + kk);
    As[(kk+0)*LDT+row]=av.x; As[(kk+1)*LDT+row]=av.y; As[(kk+2)*LDT+row]=av.z; As[(kk+3)*LDT+row]=av.w;
    Bs[(kk+0)*LDT+row]=bv.x; Bs[(kk+1)*LDT+row]=bv.y; Bs[(kk+2)*LDT+row]=bv.z; Bs[(kk+3)*LDT+row]=bv.w;
    __syncthreads();
    #pragma unroll
    for(int k=0;k<BK;k++){
      float4 a = *(const float4*)&As[k*LDT + 4*ty];
      float4 b = *(const float4*)&Bs[k*LDT + 4*tx];
      acc[0][0]+=a.x*b.x; acc[0][1]+=a.x*b.y; acc[0][2]+=a.x*b.z; acc[0][3]+=a.x*b.w;
      acc[1][0]+=a.y*b.x; acc[1][1]+=a.y*b.y; acc[1][2]+=a.y*b.z; acc[1][3]+=a.y*b.w;
      acc[2][0]+=a.z*b.x; acc[2][1]+=a.z*b.y; acc[2][2]+=a.z*b.z; acc[2][3]+=a.z*b.w;
      acc[3][0]+=a.w*b.x; acc[3][1]+=a.w*b.y; acc[3][2]+=a.w*b.z; acc[3][3]+=a.w*b.w;
    }
    __syncthreads();
  }
  const int nb = n0 + 4*tx;
  float4 bb = *(const float4*)(brd + nb);
  #pragma unroll
  for(int i=0;i<4;i++){
    int m = m0 + 4*ty + i;
    int b = m >> 5, tt = m & 31;
    float4 vt = *(const float4*)(vcAll + (size_t)(tt*B_ + b)*VCS_ + nb);
    float4 o;
    o.x = acc[i][0] + bb.x + vt.x;
    o.y = acc[i][1] + bb.y + vt.y;
    o.z = acc[i][2] + bb.z + vt.z;
    o.w = acc[i][3] + bb.w + vt.w;
    *(float4*)(out + (size_t)m*256 + nb) = o;
  }
}

// ---------------- host ----------------
extern "C" void kernel_launch(void* const* d_in, const int* in_sizes, int n_in,
                              void* d_out, int out_size, void* d_ws, size_t ws_size,
                              hipStream_t stream)
{
  const float* x     = (const float*)d_in[0];
  const float* h0    = (const float*)d_in[1];
  const float* c0    = (const float*)d_in[2];
  const float* mem0  = (const float*)d_in[3];
  const float* W_ih  = (const float*)d_in[4];
  const float* W_hh  = (const float*)d_in[5];
  const float* b_ih  = (const float*)d_in[6];
  const float* b_hh  = (const float*)d_in[7];
  const float* W_out = (const float*)d_in[8];
  const float* b_out = (const float*)d_in[9];
  const float* W_rd  = (const float*)d_in[10];
  const float* b_rd  = (const float*)d_in[11];
  const float* W_head= (const float*)d_in[12];
  const float* b_head= (const float*)d_in[13];
  // d_in[14] = K (int) — fixed at 8 by the problem setup; hard-coded in k_heads.
  float* out = (float*)d_out;

  float* ws     = (float*)d_ws;
  float* memC   = ws;                    // 128*2048*64  = 16,777,216  (slot-major [B,S,M])
  float* xg     = memC   + 16777216;     // 4096*2048    =  8,388,608  (phase A; reused in B)
  float* h_all  = xg     + 8388608;      // 32*128*512   =  2,097,152
  float* c      = h_all  + 2097152;      // 128*512      =     65,536
  float* gparts = c      + 65536;        // 4*128*2048   =  1,048,576  (phase A; = reads_all in B)
  float* reads_all = gparts;             // 4096*256     =  1,048,576  (phase B)
  // phase-B overlays inside the dead xg region (8,388,608 floats):
  float* vc_all = xg;                                                 // 4096*768 = 3,145,728
  unsigned long long* candW  = (unsigned long long*)(xg + 3145728);   // 4096 u64 (8,192 f)
  unsigned long long* candR  = candW + 4096;                          // 32768 u64 (65,536 f)
  float*              statsB = (float*)(candR + 32768);               // 5,120 f
  const size_t need = (size_t)(28377088) * sizeof(float);
  if(ws_size < need) return;  // ~113.5 MB workspace (round-4/6 proven capacity)

  hipMemcpyAsync(c, c0, 65536*sizeof(float), hipMemcpyDeviceToDevice, stream);
  hipMemcpyAsync(memC, mem0, (size_t)16777216*sizeof(float), hipMemcpyDeviceToDevice, stream);
  // xg[b*T+t, :] = x @ W_ih^T + (b_ih+b_hh)
  k_gemm64<<<dim3(64,32,1),256,0,stream>>>(x,256, W_ih,256, xg,2048, 256, b_ih,b_hh);

  // ---- phase A: LSTM recurrence (independent of memory) -> h_all ----
  for(int t=0;t<T_;t++){
    const float* hprev = (t == 0) ? h0 : (h_all + (size_t)(t-1)*65536);
    k_gemm64<<<dim3(2,32,4),256,0,stream>>>(hprev,512, W_hh,512, gparts,2048, 128, nullptr,nullptr);
    k_lstm<<<256,256,0,stream>>>(xg, gparts, h_all + (size_t)t*65536, c, t);
  }
  // ---- all vt+ctrl in one batched 64x64-tile GEMM ----
  k_vtcat<<<dim3(64,12),256,0,stream>>>(h_all, W_out,b_out, W_head,b_head, vc_all);

  // ---- phase B: memory loop (plain scores + slim heads; no fences, no delta scheme) ----
  for(int t=0;t<T_;t++){
    k_scores<<<dim3(128,4),512,0,stream>>>(memC, vc_all, t, candW, candR, statsB);
    k_heads<<<128,256,0,stream>>>(memC, vc_all, candW, candR, statsB, reads_all, t);
  }
  // ---- final output GEMM: out = reads_all @ W_rd^T + b_rd + vt ----
  k_outg<<<dim3(64,4),256,0,stream>>>(reads_all, W_rd, b_rd, vc_all, out);
}